// Round 1
// 577.949 us; speedup vs baseline: 1.0388x; 1.0388x over previous
//
#include <hip/hip_runtime.h>
#include <math.h>

#define B_   16
#define N_   4096
#define C_   512
#define CF_  256
#define NH_  8
#define HD_  32
#define FHD_ 128
#define EPS_ 1e-4f
#define PI2F 1.5707963267948966f

typedef _Float16 half8 __attribute__((ext_vector_type(8)));
typedef _Float16 half4 __attribute__((ext_vector_type(4)));
typedef _Float16 half2v __attribute__((ext_vector_type(2)));
typedef float f32x4 __attribute__((ext_vector_type(4)));
typedef unsigned short u16x8 __attribute__((ext_vector_type(8)));

__device__ __forceinline__ float abs_clamp(float t) {
    float a = fminf(fmaxf(fabsf(t), 1e-4f), 1e4f);
    return t > 0.f ? a : (t < 0.f ? -a : 0.f);
}
__device__ __forceinline__ void gld16(const void* g, void* l) {
    __builtin_amdgcn_global_load_lds(
        (const __attribute__((address_space(1))) void*)g,
        (__attribute__((address_space(3))) void*)l, 16, 0, 0);
}

// ---------------------------------------------------------------- SE: mean over tokens + f32->f16 convert of query
__global__ __launch_bounds__(256) void se_sum_kernel(const float* __restrict__ q,
                                                     float* __restrict__ sesum,
                                                     _Float16* __restrict__ q16) {
    int b = blockIdx.x, chunk = blockIdx.y;
    int t = threadIdx.x;
    int c0 = 2 * t;
    const float* p = q + ((size_t)b * N_ + (size_t)chunk * 256) * C_ + c0;
    _Float16* o = q16 + ((size_t)b * N_ + (size_t)chunk * 256) * C_ + c0;
    float a0 = 0.f, a1 = 0.f;
    for (int n = 0; n < 256; n++) {
        float2 v = *(const float2*)(p + (size_t)n * C_);
        a0 += v.x;
        a1 += v.y;
        half2v hv;
        hv[0] = (_Float16)v.x;
        hv[1] = (_Float16)v.y;
        *(half2v*)(o + (size_t)n * C_) = hv;
    }
    atomicAdd(&sesum[b * C_ + c0], a0);
    atomicAdd(&sesum[b * C_ + c0 + 1], a1);
}

// ---------------------------------------------------------------- SE: 2-layer MLP + sigmoid
__global__ __launch_bounds__(256) void se_gate_kernel(const float* __restrict__ sesum,
                                                      const float* __restrict__ Wse1,
                                                      const float* __restrict__ Wse2,
                                                      float* __restrict__ segate) {
    __shared__ float sm[C_];
    __shared__ float hm[C_ / 2];
    int b = blockIdx.x, t = threadIdx.x;
    sm[t]       = sesum[b * C_ + t]       * (1.f / N_);
    sm[t + 256] = sesum[b * C_ + t + 256] * (1.f / N_);
    __syncthreads();
    {
        const float* w = Wse1 + (size_t)t * C_;
        float acc = 0.f;
        for (int c2 = 0; c2 < C_; c2++) acc += sm[c2] * w[c2];
        hm[t] = fmaxf(acc, 0.f);
    }
    __syncthreads();
    for (int r = 0; r < 2; r++) {
        int c2 = t + r * 256;
        const float* w2 = Wse2 + (size_t)c2 * (C_ / 2);
        float a2 = 0.f;
        for (int j = 0; j < C_ / 2; j++) a2 += hm[j] * w2[j];
        segate[b * C_ + c2] = 1.f / (1.f + expf(-a2));
    }
}

// ---------------------------------------------------------------- weight convert to f16
__global__ __launch_bounds__(256) void convert_w(const float* __restrict__ Wq,
                                                 const float* __restrict__ Wk,
                                                 const float* __restrict__ Wv,
                                                 const float* __restrict__ Wo,
                                                 _Float16* __restrict__ wcat,
                                                 _Float16* __restrict__ wo16) {
    int i = blockIdx.x * 256 + threadIdx.x;
    if (i < 768 * 512) {
        int r = i >> 9, c = i & 511;
        float w = (r < 256) ? Wq[(size_t)r * 512 + c]
                : (r < 512) ? Wk[(size_t)(r - 256) * 512 + c]
                            : Wv[(size_t)(r - 512) * 512 + c];
        wcat[i] = (_Float16)w;
    } else {
        int j = i - 768 * 512;
        wo16[j] = (_Float16)Wo[j];
    }
}

// ---------------------------------------------------------------- q/k/v projection GEMM
// Block: 768 threads = 12 waves (2 M x 6 N of 64x64), tile 128 M x 384 N, K=512.
// A = q16 f16 [65536,512] (read 2x total), B = wcat f16 [768,512] (L2-resident).
// Out: q/k/v f16 (+bias, relu for q/k).
__global__ __launch_bounds__(768) void gemm_qkv(
    const _Float16* __restrict__ A16, const _Float16* __restrict__ Bw,
    const float* __restrict__ bq, const float* __restrict__ bk, const float* __restrict__ bv,
    _Float16* __restrict__ O0, _Float16* __restrict__ O1, _Float16* __restrict__ O2) {
    constexpr int K = 512;
    constexpr int NITER = K / 32;

    __shared__ __align__(16) unsigned short As[128 * 32];   // 8 KB
    __shared__ __align__(16) unsigned short Bs[384 * 32];   // 24 KB

    const int t = threadIdx.x;
    const int Mb = blockIdx.y * 128;
    const int nrow0 = blockIdx.x * 384;

    const int lane = t & 63;
    const int wv = t >> 6;               // 0..11
    const int mq = (wv & 1) * 64;
    const int nq = (wv >> 1) * 64;       // 0..320
    const int mrow = lane & 15;
    const int kq = lane >> 4;
    const int fragoff = mrow * 32 + ((kq ^ ((mrow >> 1) & 3)) * 8);

    // B staging: 1536 16B-chunks per K-step, 2 per thread, XOR chunk swizzle
    const unsigned char* bsrc[2];
    unsigned short* bdst[2];
    {
        int cid0 = t, cid1 = t + 768;
        int m0 = cid0 >> 2, c0 = (cid0 & 3) ^ ((m0 >> 1) & 3);
        int m1 = cid1 >> 2, c1 = (cid1 & 3) ^ ((m1 >> 1) & 3);
        bsrc[0] = (const unsigned char*)(Bw + (size_t)(nrow0 + m0) * K + c0 * 8);
        bsrc[1] = (const unsigned char*)(Bw + (size_t)(nrow0 + m1) * K + c1 * 8);
        bdst[0] = &Bs[cid0 * 8];
        bdst[1] = &Bs[cid1 * 8];
    }
    // A staging: 512 chunks, threads 0..511 (wave-uniform predicate)
    const unsigned char* asrc = nullptr;
    unsigned short* adst = nullptr;
    if (t < 512) {
        int m0 = t >> 2, c0 = (t & 3) ^ ((m0 >> 1) & 3);
        asrc = (const unsigned char*)(A16 + (size_t)(Mb + m0) * K + c0 * 8);
        adst = &As[t * 8];
    }

    f32x4 acc[4][4];
#pragma unroll
    for (int mi = 0; mi < 4; mi++)
#pragma unroll
        for (int ni = 0; ni < 4; ni++) acc[mi][ni] = (f32x4){0.f, 0.f, 0.f, 0.f};

#pragma unroll 1
    for (int it = 0; it < NITER; ++it) {
        __syncthreads();
        if (t < 512) gld16(asrc + it * 64, adst);
        gld16(bsrc[0] + it * 64, bdst[0]);
        gld16(bsrc[1] + it * 64, bdst[1]);
        __syncthreads();

        half8 ah[4], bh[4];
#pragma unroll
        for (int mi = 0; mi < 4; mi++)
            ah[mi] = *(const half8*)&As[(mq + mi * 16) * 32 + fragoff];
#pragma unroll
        for (int ni = 0; ni < 4; ni++)
            bh[ni] = *(const half8*)&Bs[(nq + ni * 16) * 32 + fragoff];
#pragma unroll
        for (int mi = 0; mi < 4; mi++)
#pragma unroll
            for (int ni = 0; ni < 4; ni++)
                acc[mi][ni] = __builtin_amdgcn_mfma_f32_16x16x32_f16(ah[mi], bh[ni], acc[mi][ni], 0, 0, 0);
    }

#pragma unroll
    for (int ni = 0; ni < 4; ni++) {
        int gc = nrow0 + nq + ni * 16 + mrow;   // global row of wcat = output column 0..767
        int mat = gc >> 8;                       // uniform within the 16-col fragment
        int col = gc & 255;
        const float* bias = (mat == 0) ? bq : (mat == 1) ? bk : bv;
        _Float16* O = (mat == 0) ? O0 : (mat == 1) ? O1 : O2;
        float bb = bias[col];
#pragma unroll
        for (int mi = 0; mi < 4; mi++)
#pragma unroll
            for (int r = 0; r < 4; r++) {
                int m = Mb + mq + mi * 16 + kq * 4 + r;
                float v2 = acc[mi][ni][r] + bb;
                if (mat < 2) v2 = fmaxf(v2, 0.f);
                O[(size_t)m * CF_ + col] = (_Float16)v2;
            }
    }
}

// ---------------------------------------------------------------- output projection GEMM
// Block: 1024 threads = 16 waves (2 M x 8 N of 64x64), tile 128 M x 512 N (full), K=256.
// A = ob f16 [65536,256] (read once), B = wo16 f16 [512,256] (L2-resident).
// Out fp32 (+bo, clamp, SE gate).
__global__ __launch_bounds__(1024) void gemm_out(
    const _Float16* __restrict__ A16, const _Float16* __restrict__ Bw,
    const float* __restrict__ bo, const float* __restrict__ sg,
    float* __restrict__ Of) {
    constexpr int K = 256;
    constexpr int NITER = K / 32;

    __shared__ __align__(16) unsigned short As[128 * 32];   // 8 KB
    __shared__ __align__(16) unsigned short Bs[512 * 32];   // 32 KB

    const int t = threadIdx.x;
    const int Mb = blockIdx.x * 128;

    const int lane = t & 63;
    const int wv = t >> 6;               // 0..15
    const int mq = (wv & 1) * 64;
    const int nq = (wv >> 1) * 64;       // 0..448
    const int mrow = lane & 15;
    const int kq = lane >> 4;
    const int fragoff = mrow * 32 + ((kq ^ ((mrow >> 1) & 3)) * 8);

    // B staging: 2048 chunks per K-step, 2 per thread
    const unsigned char* bsrc[2];
    unsigned short* bdst[2];
    {
        int cid0 = t, cid1 = t + 1024;
        int m0 = cid0 >> 2, c0 = (cid0 & 3) ^ ((m0 >> 1) & 3);
        int m1 = cid1 >> 2, c1 = (cid1 & 3) ^ ((m1 >> 1) & 3);
        bsrc[0] = (const unsigned char*)(Bw + (size_t)m0 * K + c0 * 8);
        bsrc[1] = (const unsigned char*)(Bw + (size_t)m1 * K + c1 * 8);
        bdst[0] = &Bs[cid0 * 8];
        bdst[1] = &Bs[cid1 * 8];
    }
    // A staging: 512 chunks, threads 0..511
    const unsigned char* asrc = nullptr;
    unsigned short* adst = nullptr;
    if (t < 512) {
        int m0 = t >> 2, c0 = (t & 3) ^ ((m0 >> 1) & 3);
        asrc = (const unsigned char*)(A16 + (size_t)(Mb + m0) * K + c0 * 8);
        adst = &As[t * 8];
    }

    f32x4 acc[4][4];
#pragma unroll
    for (int mi = 0; mi < 4; mi++)
#pragma unroll
        for (int ni = 0; ni < 4; ni++) acc[mi][ni] = (f32x4){0.f, 0.f, 0.f, 0.f};

#pragma unroll 1
    for (int it = 0; it < NITER; ++it) {
        __syncthreads();
        if (t < 512) gld16(asrc + it * 64, adst);
        gld16(bsrc[0] + it * 64, bdst[0]);
        gld16(bsrc[1] + it * 64, bdst[1]);
        __syncthreads();

        half8 ah[4], bh[4];
#pragma unroll
        for (int mi = 0; mi < 4; mi++)
            ah[mi] = *(const half8*)&As[(mq + mi * 16) * 32 + fragoff];
#pragma unroll
        for (int ni = 0; ni < 4; ni++)
            bh[ni] = *(const half8*)&Bs[(nq + ni * 16) * 32 + fragoff];
#pragma unroll
        for (int mi = 0; mi < 4; mi++)
#pragma unroll
            for (int ni = 0; ni < 4; ni++)
                acc[mi][ni] = __builtin_amdgcn_mfma_f32_16x16x32_f16(ah[mi], bh[ni], acc[mi][ni], 0, 0, 0);
    }

    int b = Mb >> 12;
#pragma unroll
    for (int ni = 0; ni < 4; ni++) {
        int gc = nq + ni * 16 + mrow;
        float bb = bo[gc];
        float gv = sg[b * C_ + gc];
#pragma unroll
        for (int mi = 0; mi < 4; mi++)
#pragma unroll
            for (int r = 0; r < 4; r++) {
                int m = Mb + mq + mi * 16 + kq * 4 + r;
                float v2 = abs_clamp(acc[mi][ni][r] + bb);
                v2 = abs_clamp(v2 * (1.f + gv));
                Of[(size_t)m * C_ + gc] = v2;
            }
    }
}

// ---------------------------------------------------------------- kv state + k_sum via f16 MFMA
__global__ __launch_bounds__(256) void kv_mfma_kernel(const _Float16* __restrict__ kin,
                                                      const _Float16* __restrict__ vin,
                                                      float* __restrict__ kvout,
                                                      float* __restrict__ ksum) {
    __shared__ __align__(16) unsigned short Ah[128 * 64];
    __shared__ __align__(16) unsigned short Bh[48 * 64];

    const int t = threadIdx.x;
    const int c8 = blockIdx.x;           // 512-token slab
    const int h = blockIdx.y, b = blockIdx.z;
    const int dp = t & 31;               // channel within head
    const int octet = t >> 5;            // token octet

    if (t < 128) {
        int r = 32 + (t & 15);
        int oc = t >> 4;
        int off = r * 64 + (((oc ^ ((r >> 3) & 7)) & 7) * 8);
        unsigned short fill = (r == 32) ? (unsigned short)0x3C00 : (unsigned short)0;
        u16x8 z = {fill, fill, fill, fill, fill, fill, fill, fill};
        *(u16x8*)&Bh[off] = z;
    }

    float cbv[8], sbv[8];
#pragma unroll
    for (int i = 0; i < 8; i++) {
        float ang = (PI2F / 64.f) * (float)(octet * 8 + i);
        cbv[i] = cosf(ang);
        sbv[i] = sinf(ang);
    }

    const int lane = t & 63;
    const int wv = t >> 6;
    const int mrow = lane & 15;
    const int kq = lane >> 4;

    f32x4 acc[2][3];
#pragma unroll
    for (int mi = 0; mi < 2; mi++)
#pragma unroll
        for (int ni = 0; ni < 3; ni++) acc[mi][ni] = (f32x4){0.f, 0.f, 0.f, 0.f};

    int offA[4];
#pragma unroll
    for (int tvar = 0; tvar < 4; tvar++) {
        int f = tvar * 32 + dp;
        offA[tvar] = f * 64 + (((octet ^ ((f >> 3) & 7)) & 7) * 8);
    }
    const int offB = dp * 64 + (((octet ^ ((dp >> 3) & 7)) & 7) * 8);

#pragma unroll 1
    for (int ch = 0; ch < 8; ch++) {
        const int n0 = c8 * 512 + ch * 64;
        const int rrow = n0 >> 6;
        float aang = (PI2F / 64.f) * (float)rrow;
        float ca = cosf(aang), sa = sinf(aang);

        const _Float16* kp = kin + ((size_t)b * N_ + n0 + octet * 8) * CF_ + h * HD_ + dp;
        const _Float16* vp = vin + ((size_t)b * N_ + n0 + octet * 8) * CF_ + h * HD_ + dp;
        float kvl[8];
        _Float16 vvl[8];
#pragma unroll
        for (int i = 0; i < 8; i++) kvl[i] = (float)kp[(size_t)i * CF_];
#pragma unroll
        for (int i = 0; i < 8; i++) vvl[i] = vp[(size_t)i * CF_];

        __syncthreads();

#pragma unroll
        for (int tvar = 0; tvar < 4; tvar++) {
            half8 hv;
#pragma unroll
            for (int i = 0; i < 8; i++) {
                float val = kvl[i] * (tvar == 0 ? ca : tvar == 1 ? sa : tvar == 2 ? cbv[i] : sbv[i]);
                hv[i] = (_Float16)val;
            }
            *(half8*)&Ah[offA[tvar]] = hv;
        }
        {
            half8 hv;
#pragma unroll
            for (int i = 0; i < 8; i++) hv[i] = vvl[i];
            *(half8*)&Bh[offB] = hv;
        }
        __syncthreads();

#pragma unroll
        for (int s = 0; s < 2; s++) {
            half8 ah[2], bh[3];
            int koct = s * 4 + kq;
#pragma unroll
            for (int mi = 0; mi < 2; mi++) {
                int f = (wv * 2 + mi) * 16 + mrow;
                ah[mi] = *(const half8*)&Ah[f * 64 + (((koct ^ ((f >> 3) & 7)) & 7) * 8)];
            }
#pragma unroll
            for (int ni = 0; ni < 3; ni++) {
                int nr = ni * 16 + mrow;
                bh[ni] = *(const half8*)&Bh[nr * 64 + (((koct ^ ((nr >> 3) & 7)) & 7) * 8)];
            }
#pragma unroll
            for (int mi = 0; mi < 2; mi++)
#pragma unroll
                for (int ni = 0; ni < 3; ni++)
                    acc[mi][ni] = __builtin_amdgcn_mfma_f32_16x16x32_f16(ah[mi], bh[ni], acc[mi][ni], 0, 0, 0);
        }
    }

    float* kvp = kvout + (size_t)(b * NH_ + h) * FHD_ * HD_;
    float* ksp = ksum + (size_t)(b * NH_ + h) * FHD_;
#pragma unroll
    for (int mi = 0; mi < 2; mi++) {
        int mt = wv * 2 + mi;
#pragma unroll
        for (int r = 0; r < 4; r++) {
            int f = mt * 16 + kq * 4 + r;
            atomicAdd(&kvp[(size_t)f * HD_ + mrow], acc[mi][0][r]);
            atomicAdd(&kvp[(size_t)f * HD_ + 16 + mrow], acc[mi][1][r]);
            if (mrow == 0) atomicAdd(&ksp[f], acc[mi][2][r]);
        }
    }
}

// ---------------------------------------------------------------- attention lookup -> f16
__global__ __launch_bounds__(256) void attn_kernel(const _Float16* __restrict__ qbuf,
                                                   const float* __restrict__ kvin,
                                                   const float* __restrict__ ksum,
                                                   _Float16* __restrict__ ob) {
    int chunk = blockIdx.x;
    int h = blockIdx.y, b = blockIdx.z;
    int t = threadIdx.x;
    __shared__ float kvS[128][32];
    __shared__ float qS[128][33];
    __shared__ float tS[128][4];
    __shared__ float ksS[128];
    __shared__ float zS[128];
    int n0 = chunk * 128;

    const float* kvp = kvin + ((size_t)(b * NH_ + h)) * FHD_ * HD_;
#pragma unroll
    for (int r = 0; r < 16; r++) {
        int idx = t + r * 256;
        (&kvS[0][0])[idx] = abs_clamp(kvp[idx]);
    }
    if (t < 128) ksS[t] = ksum[(size_t)(b * NH_ + h) * FHD_ + t];
#pragma unroll
    for (int r = 0; r < 16; r++) {
        int idx = t + r * 256;
        int tok = idx >> 5, d = idx & 31;
        qS[tok][d] = (float)qbuf[((size_t)b * N_ + n0 + tok) * CF_ + h * HD_ + d];
    }
    if (t < 128) {
        int n = n0 + t;
        float ra = (float)(n >> 6), cb = (float)(n & 63);
        float aa = (PI2F * ra) / 64.0f;
        float ab = (PI2F * cb) / 64.0f;
        tS[t][0] = cosf(aa); tS[t][1] = sinf(aa);
        tS[t][2] = cosf(ab); tS[t][3] = sinf(ab);
    }
    __syncthreads();
    if (t < 128) {
        float s = 0.f;
        for (int f = 0; f < 128; f++) s += qS[t][f & 31] * tS[t][f >> 5] * ksS[f];
        zS[t] = abs_clamp(1.f / (s + EPS_));
    }
    __syncthreads();

    int tx = t & 7, ty = t >> 3;
    float acc[4][4];
#pragma unroll
    for (int u = 0; u < 4; u++)
#pragma unroll
        for (int w = 0; w < 4; w++) acc[u][w] = 0.f;

#pragma unroll
    for (int ti = 0; ti < 4; ti++) {
        float tr0 = tS[ty * 4 + 0][ti];
        float tr1 = tS[ty * 4 + 1][ti];
        float tr2 = tS[ty * 4 + 2][ti];
        float tr3 = tS[ty * 4 + 3][ti];
        for (int dd = 0; dd < 32; dd++) {
            int f = ti * 32 + dd;
            float4 kvv = *(const float4*)&kvS[f][tx * 4];
            float q0 = qS[ty * 4 + 0][dd] * tr0;
            float q1 = qS[ty * 4 + 1][dd] * tr1;
            float q2 = qS[ty * 4 + 2][dd] * tr2;
            float q3 = qS[ty * 4 + 3][dd] * tr3;
            acc[0][0] += q0 * kvv.x; acc[0][1] += q0 * kvv.y; acc[0][2] += q0 * kvv.z; acc[0][3] += q0 * kvv.w;
            acc[1][0] += q1 * kvv.x; acc[1][1] += q1 * kvv.y; acc[1][2] += q1 * kvv.z; acc[1][3] += q1 * kvv.w;
            acc[2][0] += q2 * kvv.x; acc[2][1] += q2 * kvv.y; acc[2][2] += q2 * kvv.z; acc[2][3] += q2 * kvv.w;
            acc[3][0] += q3 * kvv.x; acc[3][1] += q3 * kvv.y; acc[3][2] += q3 * kvv.z; acc[3][3] += q3 * kvv.w;
        }
    }

#pragma unroll
    for (int u = 0; u < 4; u++) {
        int tok = ty * 4 + u;
        float z = zS[tok];
        half4 hv;
        hv[0] = (_Float16)abs_clamp(abs_clamp(acc[u][0]) * z);
        hv[1] = (_Float16)abs_clamp(abs_clamp(acc[u][1]) * z);
        hv[2] = (_Float16)abs_clamp(abs_clamp(acc[u][2]) * z);
        hv[3] = (_Float16)abs_clamp(abs_clamp(acc[u][3]) * z);
        size_t base = ((size_t)b * N_ + n0 + tok) * CF_ + h * HD_ + tx * 4;
        *(half4*)&ob[base] = hv;
    }
}

// ----------------------------------------------------------------
extern "C" void kernel_launch(void* const* d_in, const int* in_sizes, int n_in,
                              void* d_out, int out_size, void* d_ws, size_t ws_size,
                              hipStream_t stream) {
    (void)in_sizes; (void)n_in; (void)out_size; (void)ws_size;
    const float* query = (const float*)d_in[0];
    const float* Wq = (const float*)d_in[1];
    const float* bq = (const float*)d_in[2];
    const float* Wk = (const float*)d_in[3];
    const float* bk = (const float*)d_in[4];
    const float* Wv = (const float*)d_in[5];
    const float* bv = (const float*)d_in[6];
    const float* Wo = (const float*)d_in[7];
    const float* bo = (const float*)d_in[8];
    const float* Wse1 = (const float*)d_in[9];
    const float* Wse2 = (const float*)d_in[10];
    float* out = (float*)d_out;

    unsigned char* ws = (unsigned char*)d_ws;
    const size_t MB = 1024ull * 1024ull;
    // q16 [65536,512] f16, 64 MiB at offset 0. Dead after gemm_qkv.
    // ob [65536,256] f16, 32 MiB — ALIASED onto q16's region (written by attn_kernel,
    // which runs strictly after gemm_qkv has consumed q16; single stream serializes).
    _Float16* q16 = (_Float16*)(ws + 0);
    _Float16* ob  = (_Float16*)(ws + 0);
    _Float16* qb = (_Float16*)(ws + 64 * MB);   // [65536,256] f16
    _Float16* kb = (_Float16*)(ws + 96 * MB);   // [65536,256] f16
    _Float16* vb = (_Float16*)(ws + 128 * MB);  // [65536,256] f16
    _Float16* wcat = (_Float16*)(ws + 160 * MB);            // [768,512] f16, 786432 B
    _Float16* wo16 = (_Float16*)(ws + 160 * MB + 786432);   // [512,256] f16, 262144 B
    float* kvb = (float*)(ws + 161 * MB);                   // [16,8,128,32] 2 MiB
    float* ksb = (float*)(ws + 163 * MB);                   // [16,8,128]
    float* ssb = (float*)(ws + 163 * MB + 65536);           // [16,512]
    float* sgb = (float*)(ws + 163 * MB + 98304);           // [16,512]

    // zero atomic accumulators (kvb, ksb, ssb contiguous)
    hipMemsetAsync(kvb, 0, 2097152 + 65536 + 32768, stream);

    convert_w<<<2048, 256, 0, stream>>>(Wq, Wk, Wv, Wo, wcat, wo16);
    se_sum_kernel<<<dim3(B_, 16), 256, 0, stream>>>(query, ssb, q16);
    se_gate_kernel<<<B_, 256, 0, stream>>>(ssb, Wse1, Wse2, sgb);
    gemm_qkv<<<dim3(2, 512), 768, 0, stream>>>(q16, wcat, bq, bk, bv, qb, kb, vb);
    kv_mfma_kernel<<<dim3(8, NH_, B_), 256, 0, stream>>>(kb, vb, kvb, ksb);
    attn_kernel<<<dim3(32, NH_, B_), 256, 0, stream>>>(qb, kvb, ksb, ob);
    gemm_out<<<512, 1024, 0, stream>>>(ob, wo16, bo, sgb, out);
}

// Round 2
// 565.440 us; speedup vs baseline: 1.0618x; 1.0221x over previous
//
#include <hip/hip_runtime.h>
#include <math.h>

#define B_   16
#define N_   4096
#define C_   512
#define CF_  256
#define NH_  8
#define HD_  32
#define FHD_ 128
#define EPS_ 1e-4f
#define PI2F 1.5707963267948966f

typedef _Float16 half8 __attribute__((ext_vector_type(8)));
typedef _Float16 half4 __attribute__((ext_vector_type(4)));
typedef _Float16 half2v __attribute__((ext_vector_type(2)));
typedef float f32x4 __attribute__((ext_vector_type(4)));
typedef unsigned short u16x8 __attribute__((ext_vector_type(8)));

__device__ __forceinline__ float abs_clamp(float t) {
    float a = fminf(fmaxf(fabsf(t), 1e-4f), 1e4f);
    return t > 0.f ? a : (t < 0.f ? -a : 0.f);
}
__device__ __forceinline__ void gld16(const void* g, void* l) {
    __builtin_amdgcn_global_load_lds(
        (const __attribute__((address_space(1))) void*)g,
        (__attribute__((address_space(3))) void*)l, 16, 0, 0);
}

// ---------------------------------------------------------------- SE: mean over tokens + f32->f16 convert of query
__global__ __launch_bounds__(256) void se_sum_kernel(const float* __restrict__ q,
                                                     float* __restrict__ sesum,
                                                     _Float16* __restrict__ q16) {
    int b = blockIdx.x, chunk = blockIdx.y;
    int t = threadIdx.x;
    int c0 = 2 * t;
    const float* p = q + ((size_t)b * N_ + (size_t)chunk * 256) * C_ + c0;
    _Float16* o = q16 + ((size_t)b * N_ + (size_t)chunk * 256) * C_ + c0;
    float a0 = 0.f, a1 = 0.f;
    for (int n = 0; n < 256; n++) {
        float2 v = *(const float2*)(p + (size_t)n * C_);
        a0 += v.x;
        a1 += v.y;
        half2v hv;
        hv[0] = (_Float16)v.x;
        hv[1] = (_Float16)v.y;
        *(half2v*)(o + (size_t)n * C_) = hv;
    }
    atomicAdd(&sesum[b * C_ + c0], a0);
    atomicAdd(&sesum[b * C_ + c0 + 1], a1);
}

// ---------------------------------------------------------------- SE: 2-layer MLP + sigmoid
__global__ __launch_bounds__(256) void se_gate_kernel(const float* __restrict__ sesum,
                                                      const float* __restrict__ Wse1,
                                                      const float* __restrict__ Wse2,
                                                      float* __restrict__ segate) {
    __shared__ float sm[C_];
    __shared__ float hm[C_ / 2];
    int b = blockIdx.x, t = threadIdx.x;
    sm[t]       = sesum[b * C_ + t]       * (1.f / N_);
    sm[t + 256] = sesum[b * C_ + t + 256] * (1.f / N_);
    __syncthreads();
    {
        const float* w = Wse1 + (size_t)t * C_;
        float acc = 0.f;
        for (int c2 = 0; c2 < C_; c2++) acc += sm[c2] * w[c2];
        hm[t] = fmaxf(acc, 0.f);
    }
    __syncthreads();
    for (int r = 0; r < 2; r++) {
        int c2 = t + r * 256;
        const float* w2 = Wse2 + (size_t)c2 * (C_ / 2);
        float a2 = 0.f;
        for (int j = 0; j < C_ / 2; j++) a2 += hm[j] * w2[j];
        segate[b * C_ + c2] = 1.f / (1.f + expf(-a2));
    }
}

// ---------------------------------------------------------------- weight convert to f16
__global__ __launch_bounds__(256) void convert_w(const float* __restrict__ Wq,
                                                 const float* __restrict__ Wk,
                                                 const float* __restrict__ Wv,
                                                 const float* __restrict__ Wo,
                                                 _Float16* __restrict__ wcat,
                                                 _Float16* __restrict__ wo16) {
    int i = blockIdx.x * 256 + threadIdx.x;
    if (i < 768 * 512) {
        int r = i >> 9, c = i & 511;
        float w = (r < 256) ? Wq[(size_t)r * 512 + c]
                : (r < 512) ? Wk[(size_t)(r - 256) * 512 + c]
                            : Wv[(size_t)(r - 512) * 512 + c];
        wcat[i] = (_Float16)w;
    } else {
        int j = i - 768 * 512;
        wo16[j] = (_Float16)Wo[j];
    }
}

// ---------------------------------------------------------------- q/k/v projection GEMM
// Block: 768 threads = 12 waves (2 M x 6 N of 64x64), tile 128 M x 384 N, K=512.
// Double-buffered LDS: stage tile it+1 BEFORE computing tile it; single barrier
// per K-step so the global_load_lds of the next tile overlaps the MFMA phase.
__global__ __launch_bounds__(768) void gemm_qkv(
    const _Float16* __restrict__ A16, const _Float16* __restrict__ Bw,
    const float* __restrict__ bq, const float* __restrict__ bk, const float* __restrict__ bv,
    _Float16* __restrict__ O0, _Float16* __restrict__ O1, _Float16* __restrict__ O2) {
    constexpr int K = 512;
    constexpr int NITER = K / 32;

    __shared__ __align__(16) unsigned short As[2][128 * 32];   // 2 x 8 KB
    __shared__ __align__(16) unsigned short Bs[2][384 * 32];   // 2 x 24 KB

    const int t = threadIdx.x;
    const int Mb = blockIdx.y * 128;
    const int nrow0 = blockIdx.x * 384;

    const int lane = t & 63;
    const int wv = t >> 6;               // 0..11
    const int mq = (wv & 1) * 64;
    const int nq = (wv >> 1) * 64;       // 0..320
    const int mrow = lane & 15;
    const int kq = lane >> 4;
    const int fragoff = mrow * 32 + ((kq ^ ((mrow >> 1) & 3)) * 8);

    // B staging: 1536 16B-chunks per K-step, 2 per thread, XOR chunk swizzle
    const unsigned char* bsrc0;
    const unsigned char* bsrc1;
    int boff0, boff1;
    {
        int cid0 = t, cid1 = t + 768;
        int m0 = cid0 >> 2, c0 = (cid0 & 3) ^ ((m0 >> 1) & 3);
        int m1 = cid1 >> 2, c1 = (cid1 & 3) ^ ((m1 >> 1) & 3);
        bsrc0 = (const unsigned char*)(Bw + (size_t)(nrow0 + m0) * K + c0 * 8);
        bsrc1 = (const unsigned char*)(Bw + (size_t)(nrow0 + m1) * K + c1 * 8);
        boff0 = cid0 * 8;
        boff1 = cid1 * 8;
    }
    // A staging: 512 chunks, threads 0..511 (wave-uniform predicate)
    const unsigned char* asrc = nullptr;
    int aoff = 0;
    if (t < 512) {
        int m0 = t >> 2, c0 = (t & 3) ^ ((m0 >> 1) & 3);
        asrc = (const unsigned char*)(A16 + (size_t)(Mb + m0) * K + c0 * 8);
        aoff = t * 8;
    }

    f32x4 acc[4][4];
#pragma unroll
    for (int mi = 0; mi < 4; mi++)
#pragma unroll
        for (int ni = 0; ni < 4; ni++) acc[mi][ni] = (f32x4){0.f, 0.f, 0.f, 0.f};

    // prologue: stage tile 0 into buffer 0
    if (t < 512) gld16(asrc, &As[0][aoff]);
    gld16(bsrc0, &Bs[0][boff0]);
    gld16(bsrc1, &Bs[0][boff1]);
    __syncthreads();

    int cur = 0;
#pragma unroll 1
    for (int it = 0; it < NITER; ++it) {
        // issue next-tile loads into the other buffer (overlap with MFMA below)
        if (it + 1 < NITER) {
            if (t < 512) gld16(asrc + (it + 1) * 64, &As[cur ^ 1][aoff]);
            gld16(bsrc0 + (it + 1) * 64, &Bs[cur ^ 1][boff0]);
            gld16(bsrc1 + (it + 1) * 64, &Bs[cur ^ 1][boff1]);
        }

        half8 ah[4], bh[4];
#pragma unroll
        for (int mi = 0; mi < 4; mi++)
            ah[mi] = *(const half8*)&As[cur][(mq + mi * 16) * 32 + fragoff];
#pragma unroll
        for (int ni = 0; ni < 4; ni++)
            bh[ni] = *(const half8*)&Bs[cur][(nq + ni * 16) * 32 + fragoff];
#pragma unroll
        for (int mi = 0; mi < 4; mi++)
#pragma unroll
            for (int ni = 0; ni < 4; ni++)
                acc[mi][ni] = __builtin_amdgcn_mfma_f32_16x16x32_f16(ah[mi], bh[ni], acc[mi][ni], 0, 0, 0);

        if (it + 1 < NITER) __syncthreads();   // drains next-tile loads (issued pre-compute)
        cur ^= 1;
    }

#pragma unroll
    for (int ni = 0; ni < 4; ni++) {
        int gc = nrow0 + nq + ni * 16 + mrow;   // global row of wcat = output column 0..767
        int mat = gc >> 8;                       // uniform within the 16-col fragment
        int col = gc & 255;
        const float* bias = (mat == 0) ? bq : (mat == 1) ? bk : bv;
        _Float16* O = (mat == 0) ? O0 : (mat == 1) ? O1 : O2;
        float bb = bias[col];
#pragma unroll
        for (int mi = 0; mi < 4; mi++)
#pragma unroll
            for (int r = 0; r < 4; r++) {
                int m = Mb + mq + mi * 16 + kq * 4 + r;
                float v2 = acc[mi][ni][r] + bb;
                if (mat < 2) v2 = fmaxf(v2, 0.f);
                O[(size_t)m * CF_ + col] = (_Float16)v2;
            }
    }
}

// ---------------------------------------------------------------- output projection GEMM
// Block: 1024 threads = 16 waves (2 M x 8 N of 64x64), tile 128 M x 512 N (full), K=256.
// Same double-buffered prefetch-before-compute schedule.
__global__ __launch_bounds__(1024) void gemm_out(
    const _Float16* __restrict__ A16, const _Float16* __restrict__ Bw,
    const float* __restrict__ bo, const float* __restrict__ sg,
    float* __restrict__ Of) {
    constexpr int K = 256;
    constexpr int NITER = K / 32;

    __shared__ __align__(16) unsigned short As[2][128 * 32];   // 2 x 8 KB
    __shared__ __align__(16) unsigned short Bs[2][512 * 32];   // 2 x 32 KB

    const int t = threadIdx.x;
    const int Mb = blockIdx.x * 128;

    const int lane = t & 63;
    const int wv = t >> 6;               // 0..15
    const int mq = (wv & 1) * 64;
    const int nq = (wv >> 1) * 64;       // 0..448
    const int mrow = lane & 15;
    const int kq = lane >> 4;
    const int fragoff = mrow * 32 + ((kq ^ ((mrow >> 1) & 3)) * 8);

    // B staging: 2048 chunks per K-step, 2 per thread
    const unsigned char* bsrc0;
    const unsigned char* bsrc1;
    int boff0, boff1;
    {
        int cid0 = t, cid1 = t + 1024;
        int m0 = cid0 >> 2, c0 = (cid0 & 3) ^ ((m0 >> 1) & 3);
        int m1 = cid1 >> 2, c1 = (cid1 & 3) ^ ((m1 >> 1) & 3);
        bsrc0 = (const unsigned char*)(Bw + (size_t)m0 * K + c0 * 8);
        bsrc1 = (const unsigned char*)(Bw + (size_t)m1 * K + c1 * 8);
        boff0 = cid0 * 8;
        boff1 = cid1 * 8;
    }
    // A staging: 512 chunks, threads 0..511
    const unsigned char* asrc = nullptr;
    int aoff = 0;
    if (t < 512) {
        int m0 = t >> 2, c0 = (t & 3) ^ ((m0 >> 1) & 3);
        asrc = (const unsigned char*)(A16 + (size_t)(Mb + m0) * K + c0 * 8);
        aoff = t * 8;
    }

    f32x4 acc[4][4];
#pragma unroll
    for (int mi = 0; mi < 4; mi++)
#pragma unroll
        for (int ni = 0; ni < 4; ni++) acc[mi][ni] = (f32x4){0.f, 0.f, 0.f, 0.f};

    // prologue: stage tile 0 into buffer 0
    if (t < 512) gld16(asrc, &As[0][aoff]);
    gld16(bsrc0, &Bs[0][boff0]);
    gld16(bsrc1, &Bs[0][boff1]);
    __syncthreads();

    int cur = 0;
#pragma unroll 1
    for (int it = 0; it < NITER; ++it) {
        if (it + 1 < NITER) {
            if (t < 512) gld16(asrc + (it + 1) * 64, &As[cur ^ 1][aoff]);
            gld16(bsrc0 + (it + 1) * 64, &Bs[cur ^ 1][boff0]);
            gld16(bsrc1 + (it + 1) * 64, &Bs[cur ^ 1][boff1]);
        }

        half8 ah[4], bh[4];
#pragma unroll
        for (int mi = 0; mi < 4; mi++)
            ah[mi] = *(const half8*)&As[cur][(mq + mi * 16) * 32 + fragoff];
#pragma unroll
        for (int ni = 0; ni < 4; ni++)
            bh[ni] = *(const half8*)&Bs[cur][(nq + ni * 16) * 32 + fragoff];
#pragma unroll
        for (int mi = 0; mi < 4; mi++)
#pragma unroll
            for (int ni = 0; ni < 4; ni++)
                acc[mi][ni] = __builtin_amdgcn_mfma_f32_16x16x32_f16(ah[mi], bh[ni], acc[mi][ni], 0, 0, 0);

        if (it + 1 < NITER) __syncthreads();
        cur ^= 1;
    }

    int b = Mb >> 12;
#pragma unroll
    for (int ni = 0; ni < 4; ni++) {
        int gc = nq + ni * 16 + mrow;
        float bb = bo[gc];
        float gv = sg[b * C_ + gc];
#pragma unroll
        for (int mi = 0; mi < 4; mi++)
#pragma unroll
            for (int r = 0; r < 4; r++) {
                int m = Mb + mq + mi * 16 + kq * 4 + r;
                float v2 = abs_clamp(acc[mi][ni][r] + bb);
                v2 = abs_clamp(v2 * (1.f + gv));
                Of[(size_t)m * C_ + gc] = v2;
            }
    }
}

// ---------------------------------------------------------------- kv state + k_sum via f16 MFMA
__global__ __launch_bounds__(256) void kv_mfma_kernel(const _Float16* __restrict__ kin,
                                                      const _Float16* __restrict__ vin,
                                                      float* __restrict__ kvout,
                                                      float* __restrict__ ksum) {
    __shared__ __align__(16) unsigned short Ah[128 * 64];
    __shared__ __align__(16) unsigned short Bh[48 * 64];

    const int t = threadIdx.x;
    const int c8 = blockIdx.x;           // 512-token slab
    const int h = blockIdx.y, b = blockIdx.z;
    const int dp = t & 31;               // channel within head
    const int octet = t >> 5;            // token octet

    if (t < 128) {
        int r = 32 + (t & 15);
        int oc = t >> 4;
        int off = r * 64 + (((oc ^ ((r >> 3) & 7)) & 7) * 8);
        unsigned short fill = (r == 32) ? (unsigned short)0x3C00 : (unsigned short)0;
        u16x8 z = {fill, fill, fill, fill, fill, fill, fill, fill};
        *(u16x8*)&Bh[off] = z;
    }

    float cbv[8], sbv[8];
#pragma unroll
    for (int i = 0; i < 8; i++) {
        float ang = (PI2F / 64.f) * (float)(octet * 8 + i);
        cbv[i] = cosf(ang);
        sbv[i] = sinf(ang);
    }

    const int lane = t & 63;
    const int wv = t >> 6;
    const int mrow = lane & 15;
    const int kq = lane >> 4;

    f32x4 acc[2][3];
#pragma unroll
    for (int mi = 0; mi < 2; mi++)
#pragma unroll
        for (int ni = 0; ni < 3; ni++) acc[mi][ni] = (f32x4){0.f, 0.f, 0.f, 0.f};

    int offA[4];
#pragma unroll
    for (int tvar = 0; tvar < 4; tvar++) {
        int f = tvar * 32 + dp;
        offA[tvar] = f * 64 + (((octet ^ ((f >> 3) & 7)) & 7) * 8);
    }
    const int offB = dp * 64 + (((octet ^ ((dp >> 3) & 7)) & 7) * 8);

#pragma unroll 1
    for (int ch = 0; ch < 8; ch++) {
        const int n0 = c8 * 512 + ch * 64;
        const int rrow = n0 >> 6;
        float aang = (PI2F / 64.f) * (float)rrow;
        float ca = cosf(aang), sa = sinf(aang);

        const _Float16* kp = kin + ((size_t)b * N_ + n0 + octet * 8) * CF_ + h * HD_ + dp;
        const _Float16* vp = vin + ((size_t)b * N_ + n0 + octet * 8) * CF_ + h * HD_ + dp;
        float kvl[8];
        _Float16 vvl[8];
#pragma unroll
        for (int i = 0; i < 8; i++) kvl[i] = (float)kp[(size_t)i * CF_];
#pragma unroll
        for (int i = 0; i < 8; i++) vvl[i] = vp[(size_t)i * CF_];

        __syncthreads();

#pragma unroll
        for (int tvar = 0; tvar < 4; tvar++) {
            half8 hv;
#pragma unroll
            for (int i = 0; i < 8; i++) {
                float val = kvl[i] * (tvar == 0 ? ca : tvar == 1 ? sa : tvar == 2 ? cbv[i] : sbv[i]);
                hv[i] = (_Float16)val;
            }
            *(half8*)&Ah[offA[tvar]] = hv;
        }
        {
            half8 hv;
#pragma unroll
            for (int i = 0; i < 8; i++) hv[i] = vvl[i];
            *(half8*)&Bh[offB] = hv;
        }
        __syncthreads();

#pragma unroll
        for (int s = 0; s < 2; s++) {
            half8 ah[2], bh[3];
            int koct = s * 4 + kq;
#pragma unroll
            for (int mi = 0; mi < 2; mi++) {
                int f = (wv * 2 + mi) * 16 + mrow;
                ah[mi] = *(const half8*)&Ah[f * 64 + (((koct ^ ((f >> 3) & 7)) & 7) * 8)];
            }
#pragma unroll
            for (int ni = 0; ni < 3; ni++) {
                int nr = ni * 16 + mrow;
                bh[ni] = *(const half8*)&Bh[nr * 64 + (((koct ^ ((nr >> 3) & 7)) & 7) * 8)];
            }
#pragma unroll
            for (int mi = 0; mi < 2; mi++)
#pragma unroll
                for (int ni = 0; ni < 3; ni++)
                    acc[mi][ni] = __builtin_amdgcn_mfma_f32_16x16x32_f16(ah[mi], bh[ni], acc[mi][ni], 0, 0, 0);
        }
    }

    float* kvp = kvout + (size_t)(b * NH_ + h) * FHD_ * HD_;
    float* ksp = ksum + (size_t)(b * NH_ + h) * FHD_;
#pragma unroll
    for (int mi = 0; mi < 2; mi++) {
        int mt = wv * 2 + mi;
#pragma unroll
        for (int r = 0; r < 4; r++) {
            int f = mt * 16 + kq * 4 + r;
            atomicAdd(&kvp[(size_t)f * HD_ + mrow], acc[mi][0][r]);
            atomicAdd(&kvp[(size_t)f * HD_ + 16 + mrow], acc[mi][1][r]);
            if (mrow == 0) atomicAdd(&ksp[f], acc[mi][2][r]);
        }
    }
}

// ---------------------------------------------------------------- attention lookup -> f16
__global__ __launch_bounds__(256) void attn_kernel(const _Float16* __restrict__ qbuf,
                                                   const float* __restrict__ kvin,
                                                   const float* __restrict__ ksum,
                                                   _Float16* __restrict__ ob) {
    int chunk = blockIdx.x;
    int h = blockIdx.y, b = blockIdx.z;
    int t = threadIdx.x;
    __shared__ float kvS[128][32];
    __shared__ float qS[128][33];
    __shared__ float tS[128][4];
    __shared__ float ksS[128];
    __shared__ float zS[128];
    int n0 = chunk * 128;

    const float* kvp = kvin + ((size_t)(b * NH_ + h)) * FHD_ * HD_;
#pragma unroll
    for (int r = 0; r < 16; r++) {
        int idx = t + r * 256;
        (&kvS[0][0])[idx] = abs_clamp(kvp[idx]);
    }
    if (t < 128) ksS[t] = ksum[(size_t)(b * NH_ + h) * FHD_ + t];
#pragma unroll
    for (int r = 0; r < 16; r++) {
        int idx = t + r * 256;
        int tok = idx >> 5, d = idx & 31;
        qS[tok][d] = (float)qbuf[((size_t)b * N_ + n0 + tok) * CF_ + h * HD_ + d];
    }
    if (t < 128) {
        int n = n0 + t;
        float ra = (float)(n >> 6), cb = (float)(n & 63);
        float aa = (PI2F * ra) / 64.0f;
        float ab = (PI2F * cb) / 64.0f;
        tS[t][0] = cosf(aa); tS[t][1] = sinf(aa);
        tS[t][2] = cosf(ab); tS[t][3] = sinf(ab);
    }
    __syncthreads();
    if (t < 128) {
        float s = 0.f;
        for (int f = 0; f < 128; f++) s += qS[t][f & 31] * tS[t][f >> 5] * ksS[f];
        zS[t] = abs_clamp(1.f / (s + EPS_));
    }
    __syncthreads();

    int tx = t & 7, ty = t >> 3;
    float acc[4][4];
#pragma unroll
    for (int u = 0; u < 4; u++)
#pragma unroll
        for (int w = 0; w < 4; w++) acc[u][w] = 0.f;

#pragma unroll
    for (int ti = 0; ti < 4; ti++) {
        float tr0 = tS[ty * 4 + 0][ti];
        float tr1 = tS[ty * 4 + 1][ti];
        float tr2 = tS[ty * 4 + 2][ti];
        float tr3 = tS[ty * 4 + 3][ti];
        for (int dd = 0; dd < 32; dd++) {
            int f = ti * 32 + dd;
            float4 kvv = *(const float4*)&kvS[f][tx * 4];
            float q0 = qS[ty * 4 + 0][dd] * tr0;
            float q1 = qS[ty * 4 + 1][dd] * tr1;
            float q2 = qS[ty * 4 + 2][dd] * tr2;
            float q3 = qS[ty * 4 + 3][dd] * tr3;
            acc[0][0] += q0 * kvv.x; acc[0][1] += q0 * kvv.y; acc[0][2] += q0 * kvv.z; acc[0][3] += q0 * kvv.w;
            acc[1][0] += q1 * kvv.x; acc[1][1] += q1 * kvv.y; acc[1][2] += q1 * kvv.z; acc[1][3] += q1 * kvv.w;
            acc[2][0] += q2 * kvv.x; acc[2][1] += q2 * kvv.y; acc[2][2] += q2 * kvv.z; acc[2][3] += q2 * kvv.w;
            acc[3][0] += q3 * kvv.x; acc[3][1] += q3 * kvv.y; acc[3][2] += q3 * kvv.z; acc[3][3] += q3 * kvv.w;
        }
    }

#pragma unroll
    for (int u = 0; u < 4; u++) {
        int tok = ty * 4 + u;
        float z = zS[tok];
        half4 hv;
        hv[0] = (_Float16)abs_clamp(abs_clamp(acc[u][0]) * z);
        hv[1] = (_Float16)abs_clamp(abs_clamp(acc[u][1]) * z);
        hv[2] = (_Float16)abs_clamp(abs_clamp(acc[u][2]) * z);
        hv[3] = (_Float16)abs_clamp(abs_clamp(acc[u][3]) * z);
        size_t base = ((size_t)b * N_ + n0 + tok) * CF_ + h * HD_ + tx * 4;
        *(half4*)&ob[base] = hv;
    }
}

// ----------------------------------------------------------------
extern "C" void kernel_launch(void* const* d_in, const int* in_sizes, int n_in,
                              void* d_out, int out_size, void* d_ws, size_t ws_size,
                              hipStream_t stream) {
    (void)in_sizes; (void)n_in; (void)out_size; (void)ws_size;
    const float* query = (const float*)d_in[0];
    const float* Wq = (const float*)d_in[1];
    const float* bq = (const float*)d_in[2];
    const float* Wk = (const float*)d_in[3];
    const float* bk = (const float*)d_in[4];
    const float* Wv = (const float*)d_in[5];
    const float* bv = (const float*)d_in[6];
    const float* Wo = (const float*)d_in[7];
    const float* bo = (const float*)d_in[8];
    const float* Wse1 = (const float*)d_in[9];
    const float* Wse2 = (const float*)d_in[10];
    float* out = (float*)d_out;

    unsigned char* ws = (unsigned char*)d_ws;
    const size_t MB = 1024ull * 1024ull;
    // q16 [65536,512] f16, 64 MiB at offset 0. Dead after gemm_qkv.
    // ob [65536,256] f16, 32 MiB — ALIASED onto q16's region (written by attn_kernel,
    // which runs strictly after gemm_qkv has consumed q16; single stream serializes).
    _Float16* q16 = (_Float16*)(ws + 0);
    _Float16* ob  = (_Float16*)(ws + 0);
    _Float16* qb = (_Float16*)(ws + 64 * MB);   // [65536,256] f16
    _Float16* kb = (_Float16*)(ws + 96 * MB);   // [65536,256] f16
    _Float16* vb = (_Float16*)(ws + 128 * MB);  // [65536,256] f16
    _Float16* wcat = (_Float16*)(ws + 160 * MB);            // [768,512] f16, 786432 B
    _Float16* wo16 = (_Float16*)(ws + 160 * MB + 786432);   // [512,256] f16, 262144 B
    float* kvb = (float*)(ws + 161 * MB);                   // [16,8,128,32] 2 MiB
    float* ksb = (float*)(ws + 163 * MB);                   // [16,8,128]
    float* ssb = (float*)(ws + 163 * MB + 65536);           // [16,512]
    float* sgb = (float*)(ws + 163 * MB + 98304);           // [16,512]

    // zero atomic accumulators (kvb, ksb, ssb contiguous)
    hipMemsetAsync(kvb, 0, 2097152 + 65536 + 32768, stream);

    convert_w<<<2048, 256, 0, stream>>>(Wq, Wk, Wv, Wo, wcat, wo16);
    se_sum_kernel<<<dim3(B_, 16), 256, 0, stream>>>(query, ssb, q16);
    se_gate_kernel<<<B_, 256, 0, stream>>>(ssb, Wse1, Wse2, sgb);
    gemm_qkv<<<dim3(2, 512), 768, 0, stream>>>(q16, wcat, bq, bk, bv, qb, kb, vb);
    kv_mfma_kernel<<<dim3(8, NH_, B_), 256, 0, stream>>>(kb, vb, kvb, ksb);
    attn_kernel<<<dim3(32, NH_, B_), 256, 0, stream>>>(qb, kvb, ksb, ob);
    gemm_out<<<512, 1024, 0, stream>>>(ob, wo16, bo, sgb, out);
}

// Round 3
// 533.262 us; speedup vs baseline: 1.1258x; 1.0603x over previous
//
#include <hip/hip_runtime.h>
#include <math.h>

#define B_   16
#define N_   4096
#define C_   512
#define CF_  256
#define NH_  8
#define HD_  32
#define FHD_ 128
#define EPS_ 1e-4f
#define PI2F 1.5707963267948966f

typedef _Float16 half8 __attribute__((ext_vector_type(8)));
typedef _Float16 half4 __attribute__((ext_vector_type(4)));
typedef _Float16 half2v __attribute__((ext_vector_type(2)));
typedef float f32x4 __attribute__((ext_vector_type(4)));
typedef unsigned short u16x8 __attribute__((ext_vector_type(8)));

__device__ __forceinline__ float abs_clamp(float t) {
    float a = fminf(fmaxf(fabsf(t), 1e-4f), 1e4f);
    return t > 0.f ? a : (t < 0.f ? -a : 0.f);
}
__device__ __forceinline__ void gld16(const void* g, void* l) {
    __builtin_amdgcn_global_load_lds(
        (const __attribute__((address_space(1))) void*)g,
        (__attribute__((address_space(3))) void*)l, 16, 0, 0);
}

// ---------------------------------------------------------------- SE: mean over tokens + f32->f16 convert of query
__global__ __launch_bounds__(256) void se_sum_kernel(const float* __restrict__ q,
                                                     float* __restrict__ sesum,
                                                     _Float16* __restrict__ q16) {
    int b = blockIdx.x, chunk = blockIdx.y;
    int t = threadIdx.x;
    int c0 = 2 * t;
    const float* p = q + ((size_t)b * N_ + (size_t)chunk * 256) * C_ + c0;
    _Float16* o = q16 + ((size_t)b * N_ + (size_t)chunk * 256) * C_ + c0;
    float a0 = 0.f, a1 = 0.f;
    for (int n = 0; n < 256; n++) {
        float2 v = *(const float2*)(p + (size_t)n * C_);
        a0 += v.x;
        a1 += v.y;
        half2v hv;
        hv[0] = (_Float16)v.x;
        hv[1] = (_Float16)v.y;
        *(half2v*)(o + (size_t)n * C_) = hv;
    }
    atomicAdd(&sesum[b * C_ + c0], a0);
    atomicAdd(&sesum[b * C_ + c0 + 1], a1);
}

// ---------------------------------------------------------------- SE: 2-layer MLP + sigmoid
__global__ __launch_bounds__(256) void se_gate_kernel(const float* __restrict__ sesum,
                                                      const float* __restrict__ Wse1,
                                                      const float* __restrict__ Wse2,
                                                      float* __restrict__ segate) {
    __shared__ float sm[C_];
    __shared__ float hm[C_ / 2];
    int b = blockIdx.x, t = threadIdx.x;
    sm[t]       = sesum[b * C_ + t]       * (1.f / N_);
    sm[t + 256] = sesum[b * C_ + t + 256] * (1.f / N_);
    __syncthreads();
    {
        const float* w = Wse1 + (size_t)t * C_;
        float acc = 0.f;
        for (int c2 = 0; c2 < C_; c2++) acc += sm[c2] * w[c2];
        hm[t] = fmaxf(acc, 0.f);
    }
    __syncthreads();
    for (int r = 0; r < 2; r++) {
        int c2 = t + r * 256;
        const float* w2 = Wse2 + (size_t)c2 * (C_ / 2);
        float a2 = 0.f;
        for (int j = 0; j < C_ / 2; j++) a2 += hm[j] * w2[j];
        segate[b * C_ + c2] = 1.f / (1.f + expf(-a2));
    }
}

// ---------------------------------------------------------------- weight convert to f16
__global__ __launch_bounds__(256) void convert_w(const float* __restrict__ Wq,
                                                 const float* __restrict__ Wk,
                                                 const float* __restrict__ Wv,
                                                 const float* __restrict__ Wo,
                                                 _Float16* __restrict__ wcat,
                                                 _Float16* __restrict__ wo16) {
    int i = blockIdx.x * 256 + threadIdx.x;
    if (i < 768 * 512) {
        int r = i >> 9, c = i & 511;
        float w = (r < 256) ? Wq[(size_t)r * 512 + c]
                : (r < 512) ? Wk[(size_t)(r - 256) * 512 + c]
                            : Wv[(size_t)(r - 512) * 512 + c];
        wcat[i] = (_Float16)w;
    } else {
        int j = i - 768 * 512;
        wo16[j] = (_Float16)Wo[j];
    }
}

// ---------------------------------------------------------------- q/k/v projection GEMM
// Block: 768 threads = 12 waves (2 M x 6 N of 64x64), tile 128 M x 384 N, K=512.
// Double-buffered LDS, prefetch-before-compute, one barrier per K-step.
__global__ __launch_bounds__(768) void gemm_qkv(
    const _Float16* __restrict__ A16, const _Float16* __restrict__ Bw,
    const float* __restrict__ bq, const float* __restrict__ bk, const float* __restrict__ bv,
    _Float16* __restrict__ O0, _Float16* __restrict__ O1, _Float16* __restrict__ O2) {
    constexpr int K = 512;
    constexpr int NITER = K / 32;

    __shared__ __align__(16) unsigned short As[2][128 * 32];   // 2 x 8 KB
    __shared__ __align__(16) unsigned short Bs[2][384 * 32];   // 2 x 24 KB

    const int t = threadIdx.x;
    const int Mb = blockIdx.y * 128;
    const int nrow0 = blockIdx.x * 384;

    const int lane = t & 63;
    const int wv = t >> 6;               // 0..11
    const int mq = (wv & 1) * 64;
    const int nq = (wv >> 1) * 64;       // 0..320
    const int mrow = lane & 15;
    const int kq = lane >> 4;
    const int fragoff = mrow * 32 + ((kq ^ ((mrow >> 1) & 3)) * 8);

    const unsigned char* bsrc0;
    const unsigned char* bsrc1;
    int boff0, boff1;
    {
        int cid0 = t, cid1 = t + 768;
        int m0 = cid0 >> 2, c0 = (cid0 & 3) ^ ((m0 >> 1) & 3);
        int m1 = cid1 >> 2, c1 = (cid1 & 3) ^ ((m1 >> 1) & 3);
        bsrc0 = (const unsigned char*)(Bw + (size_t)(nrow0 + m0) * K + c0 * 8);
        bsrc1 = (const unsigned char*)(Bw + (size_t)(nrow0 + m1) * K + c1 * 8);
        boff0 = cid0 * 8;
        boff1 = cid1 * 8;
    }
    const unsigned char* asrc = nullptr;
    int aoff = 0;
    if (t < 512) {
        int m0 = t >> 2, c0 = (t & 3) ^ ((m0 >> 1) & 3);
        asrc = (const unsigned char*)(A16 + (size_t)(Mb + m0) * K + c0 * 8);
        aoff = t * 8;
    }

    f32x4 acc[4][4];
#pragma unroll
    for (int mi = 0; mi < 4; mi++)
#pragma unroll
        for (int ni = 0; ni < 4; ni++) acc[mi][ni] = (f32x4){0.f, 0.f, 0.f, 0.f};

    if (t < 512) gld16(asrc, &As[0][aoff]);
    gld16(bsrc0, &Bs[0][boff0]);
    gld16(bsrc1, &Bs[0][boff1]);
    __syncthreads();

    int cur = 0;
#pragma unroll 1
    for (int it = 0; it < NITER; ++it) {
        if (it + 1 < NITER) {
            if (t < 512) gld16(asrc + (it + 1) * 64, &As[cur ^ 1][aoff]);
            gld16(bsrc0 + (it + 1) * 64, &Bs[cur ^ 1][boff0]);
            gld16(bsrc1 + (it + 1) * 64, &Bs[cur ^ 1][boff1]);
        }

        half8 ah[4], bh[4];
#pragma unroll
        for (int mi = 0; mi < 4; mi++)
            ah[mi] = *(const half8*)&As[cur][(mq + mi * 16) * 32 + fragoff];
#pragma unroll
        for (int ni = 0; ni < 4; ni++)
            bh[ni] = *(const half8*)&Bs[cur][(nq + ni * 16) * 32 + fragoff];
#pragma unroll
        for (int mi = 0; mi < 4; mi++)
#pragma unroll
            for (int ni = 0; ni < 4; ni++)
                acc[mi][ni] = __builtin_amdgcn_mfma_f32_16x16x32_f16(ah[mi], bh[ni], acc[mi][ni], 0, 0, 0);

        if (it + 1 < NITER) __syncthreads();
        cur ^= 1;
    }

#pragma unroll
    for (int ni = 0; ni < 4; ni++) {
        int gc = nrow0 + nq + ni * 16 + mrow;
        int mat = gc >> 8;
        int col = gc & 255;
        const float* bias = (mat == 0) ? bq : (mat == 1) ? bk : bv;
        _Float16* O = (mat == 0) ? O0 : (mat == 1) ? O1 : O2;
        float bb = bias[col];
#pragma unroll
        for (int mi = 0; mi < 4; mi++)
#pragma unroll
            for (int r = 0; r < 4; r++) {
                int m = Mb + mq + mi * 16 + kq * 4 + r;
                float v2 = acc[mi][ni][r] + bb;
                if (mat < 2) v2 = fmaxf(v2, 0.f);
                O[(size_t)m * CF_ + col] = (_Float16)v2;
            }
    }
}

// ---------------------------------------------------------------- output projection GEMM
__global__ __launch_bounds__(1024) void gemm_out(
    const _Float16* __restrict__ A16, const _Float16* __restrict__ Bw,
    const float* __restrict__ bo, const float* __restrict__ sg,
    float* __restrict__ Of) {
    constexpr int K = 256;
    constexpr int NITER = K / 32;

    __shared__ __align__(16) unsigned short As[2][128 * 32];   // 2 x 8 KB
    __shared__ __align__(16) unsigned short Bs[2][512 * 32];   // 2 x 32 KB

    const int t = threadIdx.x;
    const int Mb = blockIdx.x * 128;

    const int lane = t & 63;
    const int wv = t >> 6;               // 0..15
    const int mq = (wv & 1) * 64;
    const int nq = (wv >> 1) * 64;       // 0..448
    const int mrow = lane & 15;
    const int kq = lane >> 4;
    const int fragoff = mrow * 32 + ((kq ^ ((mrow >> 1) & 3)) * 8);

    const unsigned char* bsrc0;
    const unsigned char* bsrc1;
    int boff0, boff1;
    {
        int cid0 = t, cid1 = t + 1024;
        int m0 = cid0 >> 2, c0 = (cid0 & 3) ^ ((m0 >> 1) & 3);
        int m1 = cid1 >> 2, c1 = (cid1 & 3) ^ ((m1 >> 1) & 3);
        bsrc0 = (const unsigned char*)(Bw + (size_t)m0 * K + c0 * 8);
        bsrc1 = (const unsigned char*)(Bw + (size_t)m1 * K + c1 * 8);
        boff0 = cid0 * 8;
        boff1 = cid1 * 8;
    }
    const unsigned char* asrc = nullptr;
    int aoff = 0;
    if (t < 512) {
        int m0 = t >> 2, c0 = (t & 3) ^ ((m0 >> 1) & 3);
        asrc = (const unsigned char*)(A16 + (size_t)(Mb + m0) * K + c0 * 8);
        aoff = t * 8;
    }

    f32x4 acc[4][4];
#pragma unroll
    for (int mi = 0; mi < 4; mi++)
#pragma unroll
        for (int ni = 0; ni < 4; ni++) acc[mi][ni] = (f32x4){0.f, 0.f, 0.f, 0.f};

    if (t < 512) gld16(asrc, &As[0][aoff]);
    gld16(bsrc0, &Bs[0][boff0]);
    gld16(bsrc1, &Bs[0][boff1]);
    __syncthreads();

    int cur = 0;
#pragma unroll 1
    for (int it = 0; it < NITER; ++it) {
        if (it + 1 < NITER) {
            if (t < 512) gld16(asrc + (it + 1) * 64, &As[cur ^ 1][aoff]);
            gld16(bsrc0 + (it + 1) * 64, &Bs[cur ^ 1][boff0]);
            gld16(bsrc1 + (it + 1) * 64, &Bs[cur ^ 1][boff1]);
        }

        half8 ah[4], bh[4];
#pragma unroll
        for (int mi = 0; mi < 4; mi++)
            ah[mi] = *(const half8*)&As[cur][(mq + mi * 16) * 32 + fragoff];
#pragma unroll
        for (int ni = 0; ni < 4; ni++)
            bh[ni] = *(const half8*)&Bs[cur][(nq + ni * 16) * 32 + fragoff];
#pragma unroll
        for (int mi = 0; mi < 4; mi++)
#pragma unroll
            for (int ni = 0; ni < 4; ni++)
                acc[mi][ni] = __builtin_amdgcn_mfma_f32_16x16x32_f16(ah[mi], bh[ni], acc[mi][ni], 0, 0, 0);

        if (it + 1 < NITER) __syncthreads();
        cur ^= 1;
    }

    int b = Mb >> 12;
#pragma unroll
    for (int ni = 0; ni < 4; ni++) {
        int gc = nq + ni * 16 + mrow;
        float bb = bo[gc];
        float gv = sg[b * C_ + gc];
#pragma unroll
        for (int mi = 0; mi < 4; mi++)
#pragma unroll
            for (int r = 0; r < 4; r++) {
                int m = Mb + mq + mi * 16 + kq * 4 + r;
                float v2 = abs_clamp(acc[mi][ni][r] + bb);
                v2 = abs_clamp(v2 * (1.f + gv));
                Of[(size_t)m * C_ + gc] = v2;
            }
    }
}

// ---------------------------------------------------------------- kv state + k_sum via f16 MFMA
// Output now TRANSPOSED: kvout is [b][h][d=32][f=128] so attn can stage it as a
// K-major MFMA B-operand directly.
__global__ __launch_bounds__(256) void kv_mfma_kernel(const _Float16* __restrict__ kin,
                                                      const _Float16* __restrict__ vin,
                                                      float* __restrict__ kvout,
                                                      float* __restrict__ ksum) {
    __shared__ __align__(16) unsigned short Ah[128 * 64];
    __shared__ __align__(16) unsigned short Bh[48 * 64];

    const int t = threadIdx.x;
    const int c8 = blockIdx.x;           // 512-token slab
    const int h = blockIdx.y, b = blockIdx.z;
    const int dp = t & 31;               // channel within head
    const int octet = t >> 5;            // token octet

    if (t < 128) {
        int r = 32 + (t & 15);
        int oc = t >> 4;
        int off = r * 64 + (((oc ^ ((r >> 3) & 7)) & 7) * 8);
        unsigned short fill = (r == 32) ? (unsigned short)0x3C00 : (unsigned short)0;
        u16x8 z = {fill, fill, fill, fill, fill, fill, fill, fill};
        *(u16x8*)&Bh[off] = z;
    }

    float cbv[8], sbv[8];
#pragma unroll
    for (int i = 0; i < 8; i++) {
        float ang = (PI2F / 64.f) * (float)(octet * 8 + i);
        cbv[i] = cosf(ang);
        sbv[i] = sinf(ang);
    }

    const int lane = t & 63;
    const int wv = t >> 6;
    const int mrow = lane & 15;
    const int kq = lane >> 4;

    f32x4 acc[2][3];
#pragma unroll
    for (int mi = 0; mi < 2; mi++)
#pragma unroll
        for (int ni = 0; ni < 3; ni++) acc[mi][ni] = (f32x4){0.f, 0.f, 0.f, 0.f};

    int offA[4];
#pragma unroll
    for (int tvar = 0; tvar < 4; tvar++) {
        int f = tvar * 32 + dp;
        offA[tvar] = f * 64 + (((octet ^ ((f >> 3) & 7)) & 7) * 8);
    }
    const int offB = dp * 64 + (((octet ^ ((dp >> 3) & 7)) & 7) * 8);

#pragma unroll 1
    for (int ch = 0; ch < 8; ch++) {
        const int n0 = c8 * 512 + ch * 64;
        const int rrow = n0 >> 6;
        float aang = (PI2F / 64.f) * (float)rrow;
        float ca = cosf(aang), sa = sinf(aang);

        const _Float16* kp = kin + ((size_t)b * N_ + n0 + octet * 8) * CF_ + h * HD_ + dp;
        const _Float16* vp = vin + ((size_t)b * N_ + n0 + octet * 8) * CF_ + h * HD_ + dp;
        float kvl[8];
        _Float16 vvl[8];
#pragma unroll
        for (int i = 0; i < 8; i++) kvl[i] = (float)kp[(size_t)i * CF_];
#pragma unroll
        for (int i = 0; i < 8; i++) vvl[i] = vp[(size_t)i * CF_];

        __syncthreads();

#pragma unroll
        for (int tvar = 0; tvar < 4; tvar++) {
            half8 hv;
#pragma unroll
            for (int i = 0; i < 8; i++) {
                float val = kvl[i] * (tvar == 0 ? ca : tvar == 1 ? sa : tvar == 2 ? cbv[i] : sbv[i]);
                hv[i] = (_Float16)val;
            }
            *(half8*)&Ah[offA[tvar]] = hv;
        }
        {
            half8 hv;
#pragma unroll
            for (int i = 0; i < 8; i++) hv[i] = vvl[i];
            *(half8*)&Bh[offB] = hv;
        }
        __syncthreads();

#pragma unroll
        for (int s = 0; s < 2; s++) {
            half8 ah[2], bh[3];
            int koct = s * 4 + kq;
#pragma unroll
            for (int mi = 0; mi < 2; mi++) {
                int f = (wv * 2 + mi) * 16 + mrow;
                ah[mi] = *(const half8*)&Ah[f * 64 + (((koct ^ ((f >> 3) & 7)) & 7) * 8)];
            }
#pragma unroll
            for (int ni = 0; ni < 3; ni++) {
                int nr = ni * 16 + mrow;
                bh[ni] = *(const half8*)&Bh[nr * 64 + (((koct ^ ((nr >> 3) & 7)) & 7) * 8)];
            }
#pragma unroll
            for (int mi = 0; mi < 2; mi++)
#pragma unroll
                for (int ni = 0; ni < 3; ni++)
                    acc[mi][ni] = __builtin_amdgcn_mfma_f32_16x16x32_f16(ah[mi], bh[ni], acc[mi][ni], 0, 0, 0);
        }
    }

    // transposed store: kvout[b][h][d][f]
    float* kvp = kvout + (size_t)(b * NH_ + h) * FHD_ * HD_;
    float* ksp = ksum + (size_t)(b * NH_ + h) * FHD_;
#pragma unroll
    for (int mi = 0; mi < 2; mi++) {
        int mt = wv * 2 + mi;
#pragma unroll
        for (int r = 0; r < 4; r++) {
            int f = mt * 16 + kq * 4 + r;
            atomicAdd(&kvp[(size_t)mrow * FHD_ + f], acc[mi][0][r]);
            atomicAdd(&kvp[(size_t)(16 + mrow) * FHD_ + f], acc[mi][1][r]);
            if (mrow == 0) atomicAdd(&ksp[f], acc[mi][2][r]);
        }
    }
}

// ---------------------------------------------------------------- attention lookup via MFMA -> f16
// Per block: (b, h, 128 tokens). C[128 tok][48] = A[128][128 f] * B[48][128 f]^T(K-major)
// where B rows 0..31 = abs_clamp(KV^T) f16, row 32 = ksum f16 (z-denominator for free),
// rows 33..47 zero. XOR swizzle (chunk ^ row&7) on both LDS operands.
__global__ __launch_bounds__(256) void attn_kernel(const _Float16* __restrict__ qbuf,
                                                   const float* __restrict__ kvin,
                                                   const float* __restrict__ ksum,
                                                   _Float16* __restrict__ ob) {
    __shared__ __align__(16) unsigned short Aq[128 * 128];   // 32 KB
    __shared__ __align__(16) unsigned short Bk[48 * 128];    // 12 KB
    __shared__ float zS[128];

    const int chunk = blockIdx.x;
    const int h = blockIdx.y, b = blockIdx.z;
    const int t = threadIdx.x;
    const int n0 = chunk * 128;

    // ---- stage B
    {
        const float* kvp = kvin + ((size_t)(b * NH_ + h)) * (HD_ * FHD_);
        int d = t >> 3;            // 0..31
        int c0 = (t & 7) * 2;
#pragma unroll
        for (int cc = 0; cc < 2; cc++) {
            int c = c0 + cc;
            const float* src = kvp + (size_t)d * FHD_ + c * 8;
            half8 hv;
#pragma unroll
            for (int i = 0; i < 8; i++) hv[i] = (_Float16)abs_clamp(src[i]);
            *(half8*)&Bk[d * 128 + ((c ^ (d & 7)) * 8)] = hv;
        }
        if (t < 16) {
            const float* ks = ksum + ((size_t)(b * NH_ + h)) * FHD_ + t * 8;
            half8 hv;
#pragma unroll
            for (int i = 0; i < 8; i++) hv[i] = (_Float16)ks[i];
            *(half8*)&Bk[32 * 128 + (t * 8)] = hv;        // 32&7==0, no swizzle shift
        } else {
            int idx = t - 16;                              // 240 chunks, rows 33..47
            int r = 33 + (idx >> 4), c = idx & 15;
            half8 z = {};
            *(half8*)&Bk[r * 128 + ((c ^ (r & 7)) * 8)] = z;
        }
    }
    // ---- stage A: q_ expanded [tok][f], f16, swizzled
    {
        int tok = t >> 1, hf = t & 1;
        int n = n0 + tok;
        const _Float16* qp = qbuf + ((size_t)b * N_ + n) * CF_ + h * HD_;
        half8 q0 = *(const half8*)(qp + 0);
        half8 q1 = *(const half8*)(qp + 8);
        half8 q2 = *(const half8*)(qp + 16);
        half8 q3 = *(const half8*)(qp + 24);
        float f0, f1;
        if (hf == 0) {
            float aa = (PI2F / 64.f) * (float)(n >> 6);
            f0 = cosf(aa); f1 = sinf(aa);
        } else {
            float ab = (PI2F / 64.f) * (float)(n & 63);
            f0 = cosf(ab); f1 = sinf(ab);
        }
#pragma unroll
        for (int ti = 0; ti < 2; ti++) {
            float fac = ti ? f1 : f0;
#pragma unroll
            for (int dc = 0; dc < 4; dc++) {
                half8 qv = (dc == 0) ? q0 : (dc == 1) ? q1 : (dc == 2) ? q2 : q3;
                half8 hv;
#pragma unroll
                for (int i = 0; i < 8; i++) hv[i] = (_Float16)((float)qv[i] * fac);
                int c = hf * 8 + ti * 4 + dc;
                *(half8*)&Aq[tok * 128 + ((c ^ (tok & 7)) * 8)] = hv;
            }
        }
    }
    __syncthreads();

    const int lane = t & 63;
    const int wv = t >> 6;            // wave handles tokens [wv*32, wv*32+32)
    const int mrow = lane & 15;
    const int kq = lane >> 4;

    f32x4 acc[2][3];
#pragma unroll
    for (int mi = 0; mi < 2; mi++)
#pragma unroll
        for (int ni = 0; ni < 3; ni++) acc[mi][ni] = (f32x4){0.f, 0.f, 0.f, 0.f};

#pragma unroll
    for (int ks = 0; ks < 4; ks++) {
        half8 ah[2], bh[3];
        int cpos = ks * 4 + kq;
#pragma unroll
        for (int mi = 0; mi < 2; mi++) {
            int row = wv * 32 + mi * 16 + mrow;
            ah[mi] = *(const half8*)&Aq[row * 128 + ((cpos ^ (row & 7)) * 8)];
        }
#pragma unroll
        for (int ni = 0; ni < 3; ni++) {
            int row = ni * 16 + mrow;
            bh[ni] = *(const half8*)&Bk[row * 128 + ((cpos ^ (row & 7)) * 8)];
        }
#pragma unroll
        for (int mi = 0; mi < 2; mi++)
#pragma unroll
            for (int ni = 0; ni < 3; ni++)
                acc[mi][ni] = __builtin_amdgcn_mfma_f32_16x16x32_f16(ah[mi], bh[ni], acc[mi][ni], 0, 0, 0);
    }

    // z-sums live in C column 32 (ni=2, col offset 0) -> lanes with mrow==0
    if (mrow == 0) {
#pragma unroll
        for (int mi = 0; mi < 2; mi++)
#pragma unroll
            for (int r = 0; r < 4; r++)
                zS[wv * 32 + mi * 16 + kq * 4 + r] = acc[mi][2][r];
    }
    __syncthreads();

#pragma unroll
    for (int mi = 0; mi < 2; mi++) {
#pragma unroll
        for (int r = 0; r < 4; r++) {
            int tok = wv * 32 + mi * 16 + kq * 4 + r;
            float z = abs_clamp(1.f / (zS[tok] + EPS_));
            float v0 = abs_clamp(abs_clamp(acc[mi][0][r]) * z);
            float v1 = abs_clamp(abs_clamp(acc[mi][1][r]) * z);
            size_t base = ((size_t)b * N_ + n0 + tok) * CF_ + h * HD_;
            ob[base + mrow] = (_Float16)v0;
            ob[base + 16 + mrow] = (_Float16)v1;
        }
    }
}

// ----------------------------------------------------------------
extern "C" void kernel_launch(void* const* d_in, const int* in_sizes, int n_in,
                              void* d_out, int out_size, void* d_ws, size_t ws_size,
                              hipStream_t stream) {
    (void)in_sizes; (void)n_in; (void)out_size; (void)ws_size;
    const float* query = (const float*)d_in[0];
    const float* Wq = (const float*)d_in[1];
    const float* bq = (const float*)d_in[2];
    const float* Wk = (const float*)d_in[3];
    const float* bk = (const float*)d_in[4];
    const float* Wv = (const float*)d_in[5];
    const float* bv = (const float*)d_in[6];
    const float* Wo = (const float*)d_in[7];
    const float* bo = (const float*)d_in[8];
    const float* Wse1 = (const float*)d_in[9];
    const float* Wse2 = (const float*)d_in[10];
    float* out = (float*)d_out;

    unsigned char* ws = (unsigned char*)d_ws;
    const size_t MB = 1024ull * 1024ull;
    // q16 [65536,512] f16, 64 MiB at offset 0. Dead after gemm_qkv.
    // ob [65536,256] f16, 32 MiB — aliased onto q16's region (attn runs after
    // gemm_qkv has consumed q16; single stream serializes).
    _Float16* q16 = (_Float16*)(ws + 0);
    _Float16* ob  = (_Float16*)(ws + 0);
    _Float16* qb = (_Float16*)(ws + 64 * MB);   // [65536,256] f16
    _Float16* kb = (_Float16*)(ws + 96 * MB);   // [65536,256] f16
    _Float16* vb = (_Float16*)(ws + 128 * MB);  // [65536,256] f16
    _Float16* wcat = (_Float16*)(ws + 160 * MB);            // [768,512] f16
    _Float16* wo16 = (_Float16*)(ws + 160 * MB + 786432);   // [512,256] f16
    float* kvb = (float*)(ws + 161 * MB);                   // [16,8,32,128] f32 (transposed), 2 MiB
    float* ksb = (float*)(ws + 163 * MB);                   // [16,8,128]
    float* ssb = (float*)(ws + 163 * MB + 65536);           // [16,512]
    float* sgb = (float*)(ws + 163 * MB + 98304);           // [16,512]

    // zero atomic accumulators (kvb, ksb, ssb contiguous)
    hipMemsetAsync(kvb, 0, 2097152 + 65536 + 32768, stream);

    convert_w<<<2048, 256, 0, stream>>>(Wq, Wk, Wv, Wo, wcat, wo16);
    se_sum_kernel<<<dim3(B_, 16), 256, 0, stream>>>(query, ssb, q16);
    se_gate_kernel<<<B_, 256, 0, stream>>>(ssb, Wse1, Wse2, sgb);
    gemm_qkv<<<dim3(2, 512), 768, 0, stream>>>(q16, wcat, bq, bk, bv, qb, kb, vb);
    kv_mfma_kernel<<<dim3(8, NH_, B_), 256, 0, stream>>>(kb, vb, kvb, ksb);
    attn_kernel<<<dim3(32, NH_, B_), 256, 0, stream>>>(qb, kvb, ksb, ob);
    gemm_out<<<512, 1024, 0, stream>>>(ob, wo16, bo, sgb, out);
}

// Round 4
// 509.050 us; speedup vs baseline: 1.1794x; 1.0476x over previous
//
#include <hip/hip_runtime.h>
#include <math.h>

#define B_   16
#define N_   4096
#define C_   512
#define CF_  256
#define NH_  8
#define HD_  32
#define FHD_ 128
#define BN_  (B_ * N_)   // 65536
#define EPS_ 1e-4f
#define PI2F 1.5707963267948966f

typedef _Float16 half8 __attribute__((ext_vector_type(8)));
typedef _Float16 half4 __attribute__((ext_vector_type(4)));
typedef _Float16 half2v __attribute__((ext_vector_type(2)));
typedef float f32x4 __attribute__((ext_vector_type(4)));
typedef unsigned short u16x8 __attribute__((ext_vector_type(8)));

__device__ __forceinline__ float abs_clamp(float t) {
    float a = fminf(fmaxf(fabsf(t), 1e-4f), 1e4f);
    return t > 0.f ? a : (t < 0.f ? -a : 0.f);
}
__device__ __forceinline__ void gld16(const void* g, void* l) {
    __builtin_amdgcn_global_load_lds(
        (const __attribute__((address_space(1))) void*)g,
        (__attribute__((address_space(3))) void*)l, 16, 0, 0);
}

// ---------------------------------------------------------------- SE: mean over tokens + f32->f16 convert of query
__global__ __launch_bounds__(256) void se_sum_kernel(const float* __restrict__ q,
                                                     float* __restrict__ sesum,
                                                     _Float16* __restrict__ q16) {
    int b = blockIdx.x, chunk = blockIdx.y;
    int t = threadIdx.x;
    int c0 = 2 * t;
    const float* p = q + ((size_t)b * N_ + (size_t)chunk * 256) * C_ + c0;
    _Float16* o = q16 + ((size_t)b * N_ + (size_t)chunk * 256) * C_ + c0;
    float a0 = 0.f, a1 = 0.f;
    for (int n = 0; n < 256; n++) {
        float2 v = *(const float2*)(p + (size_t)n * C_);
        a0 += v.x;
        a1 += v.y;
        half2v hv;
        hv[0] = (_Float16)v.x;
        hv[1] = (_Float16)v.y;
        *(half2v*)(o + (size_t)n * C_) = hv;
    }
    atomicAdd(&sesum[b * C_ + c0], a0);
    atomicAdd(&sesum[b * C_ + c0 + 1], a1);
}

// ---------------------------------------------------------------- SE: 2-layer MLP + sigmoid
__global__ __launch_bounds__(256) void se_gate_kernel(const float* __restrict__ sesum,
                                                      const float* __restrict__ Wse1,
                                                      const float* __restrict__ Wse2,
                                                      float* __restrict__ segate) {
    __shared__ float sm[C_];
    __shared__ float hm[C_ / 2];
    int b = blockIdx.x, t = threadIdx.x;
    sm[t]       = sesum[b * C_ + t]       * (1.f / N_);
    sm[t + 256] = sesum[b * C_ + t + 256] * (1.f / N_);
    __syncthreads();
    {
        const float* w = Wse1 + (size_t)t * C_;
        float acc = 0.f;
        for (int c2 = 0; c2 < C_; c2++) acc += sm[c2] * w[c2];
        hm[t] = fmaxf(acc, 0.f);
    }
    __syncthreads();
    for (int r = 0; r < 2; r++) {
        int c2 = t + r * 256;
        const float* w2 = Wse2 + (size_t)c2 * (C_ / 2);
        float a2 = 0.f;
        for (int j = 0; j < C_ / 2; j++) a2 += hm[j] * w2[j];
        segate[b * C_ + c2] = 1.f / (1.f + expf(-a2));
    }
}

// ---------------------------------------------------------------- weight convert to f16
__global__ __launch_bounds__(256) void convert_w(const float* __restrict__ Wq,
                                                 const float* __restrict__ Wk,
                                                 const float* __restrict__ Wv,
                                                 const float* __restrict__ Wo,
                                                 _Float16* __restrict__ wcat,
                                                 _Float16* __restrict__ wo16) {
    int i = blockIdx.x * 256 + threadIdx.x;
    if (i < 768 * 512) {
        int r = i >> 9, c = i & 511;
        float w = (r < 256) ? Wq[(size_t)r * 512 + c]
                : (r < 512) ? Wk[(size_t)(r - 256) * 512 + c]
                            : Wv[(size_t)(r - 512) * 512 + c];
        wcat[i] = (_Float16)w;
    } else {
        int j = i - 768 * 512;
        wo16[j] = (_Float16)Wo[j];
    }
}

// ---------------------------------------------------------------- q/k/v projection GEMM
// 256 threads = 4 waves (2Mx2N of 64x64), tile 128M x 128N, K=512, dbuf LDS.
// Grid 3072 blocks, XCD-chunked swizzle: all 6 N-tiles of an M-slab land on the
// same XCD so the A slab is read from HBM once and served from that XCD's L2.
// k and v are stored TRANSPOSED [col=256][M=65536] for kv_mfma's coalesced loads.
__global__ __launch_bounds__(256) void gemm_qkv(
    const _Float16* __restrict__ A16, const _Float16* __restrict__ Bw,
    const float* __restrict__ bq, const float* __restrict__ bk, const float* __restrict__ bv,
    _Float16* __restrict__ Oq, _Float16* __restrict__ kT, _Float16* __restrict__ vT) {
    constexpr int K = 512;
    constexpr int NITER = K / 32;

    __shared__ __align__(16) unsigned short As[2][128 * 32];   // 2 x 8 KB
    __shared__ __align__(16) unsigned short Bs[2][128 * 32];   // 2 x 8 KB

    const int t = threadIdx.x;
    // XCD-chunked swizzle: nwg=3072, 8 XCDs, 384 blocks per XCD chunk.
    const int did = blockIdx.x + 6 * blockIdx.y;
    const int lid = (did & 7) * 384 + (did >> 3);
    const int bx = lid % 6;
    const int Mb = (lid / 6) * 128;
    const int nrow0 = bx * 128;

    const int lane = t & 63;
    const int wv = t >> 6;
    const int mq = (wv >> 1) * 64;
    const int nq = (wv & 1) * 64;
    const int mrow = lane & 15;
    const int kq = lane >> 4;
    const int fragoff = mrow * 32 + ((kq ^ ((mrow >> 1) & 3)) * 8);

    // staging: 512 chunks each for A and B per K-step; 2 per thread each.
    const unsigned char *asrc0, *asrc1, *bsrc0, *bsrc1;
    int off0, off1;
    {
        int cid0 = t, cid1 = t + 256;
        int m0 = cid0 >> 2, c0 = (cid0 & 3) ^ ((m0 >> 1) & 3);
        int m1 = cid1 >> 2, c1 = (cid1 & 3) ^ ((m1 >> 1) & 3);
        asrc0 = (const unsigned char*)(A16 + (size_t)(Mb + m0) * K + c0 * 8);
        asrc1 = (const unsigned char*)(A16 + (size_t)(Mb + m1) * K + c1 * 8);
        bsrc0 = (const unsigned char*)(Bw + (size_t)(nrow0 + m0) * K + c0 * 8);
        bsrc1 = (const unsigned char*)(Bw + (size_t)(nrow0 + m1) * K + c1 * 8);
        off0 = cid0 * 8;
        off1 = cid1 * 8;
    }

    f32x4 acc[4][4];
#pragma unroll
    for (int mi = 0; mi < 4; mi++)
#pragma unroll
        for (int ni = 0; ni < 4; ni++) acc[mi][ni] = (f32x4){0.f, 0.f, 0.f, 0.f};

    // prologue: stage tile 0 into buffer 0
    gld16(asrc0, &As[0][off0]);
    gld16(asrc1, &As[0][off1]);
    gld16(bsrc0, &Bs[0][off0]);
    gld16(bsrc1, &Bs[0][off1]);
    __syncthreads();

    int cur = 0;
#pragma unroll 1
    for (int it = 0; it < NITER; ++it) {
        if (it + 1 < NITER) {
            gld16(asrc0 + (it + 1) * 64, &As[cur ^ 1][off0]);
            gld16(asrc1 + (it + 1) * 64, &As[cur ^ 1][off1]);
            gld16(bsrc0 + (it + 1) * 64, &Bs[cur ^ 1][off0]);
            gld16(bsrc1 + (it + 1) * 64, &Bs[cur ^ 1][off1]);
        }

        half8 ah[4], bh[4];
#pragma unroll
        for (int mi = 0; mi < 4; mi++)
            ah[mi] = *(const half8*)&As[cur][(mq + mi * 16) * 32 + fragoff];
#pragma unroll
        for (int ni = 0; ni < 4; ni++)
            bh[ni] = *(const half8*)&Bs[cur][(nq + ni * 16) * 32 + fragoff];
#pragma unroll
        for (int mi = 0; mi < 4; mi++)
#pragma unroll
            for (int ni = 0; ni < 4; ni++)
                acc[mi][ni] = __builtin_amdgcn_mfma_f32_16x16x32_f16(ah[mi], bh[ni], acc[mi][ni], 0, 0, 0);

        if (it + 1 < NITER) __syncthreads();
        cur ^= 1;
    }

#pragma unroll
    for (int ni = 0; ni < 4; ni++) {
        int gc = nrow0 + nq + ni * 16 + mrow;   // output column 0..767
        int mat = gc >> 8;                       // wave-uniform (mrow spans 16)
        int col = gc & 255;
        float bb = (mat == 0 ? bq : mat == 1 ? bk : bv)[col];
        if (mat == 0) {
#pragma unroll
            for (int mi = 0; mi < 4; mi++)
#pragma unroll
                for (int r = 0; r < 4; r++) {
                    int m = Mb + mq + mi * 16 + kq * 4 + r;
                    float v2 = fmaxf(acc[mi][ni][r] + bb, 0.f);
                    Oq[(size_t)m * CF_ + col] = (_Float16)v2;
                }
        } else {
            _Float16* OT = (mat == 1) ? kT : vT;
#pragma unroll
            for (int mi = 0; mi < 4; mi++) {
                int m0r = Mb + mq + mi * 16 + kq * 4;
                half4 hv;
#pragma unroll
                for (int r = 0; r < 4; r++) {
                    float v2 = acc[mi][ni][r] + bb;
                    if (mat == 1) v2 = fmaxf(v2, 0.f);
                    hv[r] = (_Float16)v2;
                }
                *(half4*)&OT[(size_t)col * BN_ + m0r] = hv;
            }
        }
    }
}

// ---------------------------------------------------------------- output projection GEMM
// 256 threads, tile 128M x 128N, K=256, dbuf LDS, XCD-chunked swizzle (nwg=2048).
__global__ __launch_bounds__(256) void gemm_out(
    const _Float16* __restrict__ A16, const _Float16* __restrict__ Bw,
    const float* __restrict__ bo, const float* __restrict__ sg,
    float* __restrict__ Of) {
    constexpr int K = 256;
    constexpr int NITER = K / 32;

    __shared__ __align__(16) unsigned short As[2][128 * 32];
    __shared__ __align__(16) unsigned short Bs[2][128 * 32];

    const int t = threadIdx.x;
    const int did = blockIdx.x + 4 * blockIdx.y;
    const int lid = (did & 7) * 256 + (did >> 3);
    const int bx = lid & 3;
    const int Mb = (lid >> 2) * 128;
    const int nrow0 = bx * 128;

    const int lane = t & 63;
    const int wv = t >> 6;
    const int mq = (wv >> 1) * 64;
    const int nq = (wv & 1) * 64;
    const int mrow = lane & 15;
    const int kq = lane >> 4;
    const int fragoff = mrow * 32 + ((kq ^ ((mrow >> 1) & 3)) * 8);

    const unsigned char *asrc0, *asrc1, *bsrc0, *bsrc1;
    int off0, off1;
    {
        int cid0 = t, cid1 = t + 256;
        int m0 = cid0 >> 2, c0 = (cid0 & 3) ^ ((m0 >> 1) & 3);
        int m1 = cid1 >> 2, c1 = (cid1 & 3) ^ ((m1 >> 1) & 3);
        asrc0 = (const unsigned char*)(A16 + (size_t)(Mb + m0) * K + c0 * 8);
        asrc1 = (const unsigned char*)(A16 + (size_t)(Mb + m1) * K + c1 * 8);
        bsrc0 = (const unsigned char*)(Bw + (size_t)(nrow0 + m0) * K + c0 * 8);
        bsrc1 = (const unsigned char*)(Bw + (size_t)(nrow0 + m1) * K + c1 * 8);
        off0 = cid0 * 8;
        off1 = cid1 * 8;
    }

    f32x4 acc[4][4];
#pragma unroll
    for (int mi = 0; mi < 4; mi++)
#pragma unroll
        for (int ni = 0; ni < 4; ni++) acc[mi][ni] = (f32x4){0.f, 0.f, 0.f, 0.f};

    gld16(asrc0, &As[0][off0]);
    gld16(asrc1, &As[0][off1]);
    gld16(bsrc0, &Bs[0][off0]);
    gld16(bsrc1, &Bs[0][off1]);
    __syncthreads();

    int cur = 0;
#pragma unroll 1
    for (int it = 0; it < NITER; ++it) {
        if (it + 1 < NITER) {
            gld16(asrc0 + (it + 1) * 64, &As[cur ^ 1][off0]);
            gld16(asrc1 + (it + 1) * 64, &As[cur ^ 1][off1]);
            gld16(bsrc0 + (it + 1) * 64, &Bs[cur ^ 1][off0]);
            gld16(bsrc1 + (it + 1) * 64, &Bs[cur ^ 1][off1]);
        }

        half8 ah[4], bh[4];
#pragma unroll
        for (int mi = 0; mi < 4; mi++)
            ah[mi] = *(const half8*)&As[cur][(mq + mi * 16) * 32 + fragoff];
#pragma unroll
        for (int ni = 0; ni < 4; ni++)
            bh[ni] = *(const half8*)&Bs[cur][(nq + ni * 16) * 32 + fragoff];
#pragma unroll
        for (int mi = 0; mi < 4; mi++)
#pragma unroll
            for (int ni = 0; ni < 4; ni++)
                acc[mi][ni] = __builtin_amdgcn_mfma_f32_16x16x32_f16(ah[mi], bh[ni], acc[mi][ni], 0, 0, 0);

        if (it + 1 < NITER) __syncthreads();
        cur ^= 1;
    }

    int b = Mb >> 12;
#pragma unroll
    for (int ni = 0; ni < 4; ni++) {
        int gc = nrow0 + nq + ni * 16 + mrow;
        float bb = bo[gc];
        float gv = sg[b * C_ + gc];
#pragma unroll
        for (int mi = 0; mi < 4; mi++)
#pragma unroll
            for (int r = 0; r < 4; r++) {
                int m = Mb + mq + mi * 16 + kq * 4 + r;
                float v2 = abs_clamp(acc[mi][ni][r] + bb);
                v2 = abs_clamp(v2 * (1.f + gv));
                Of[(size_t)m * C_ + gc] = v2;
            }
    }
}

// ---------------------------------------------------------------- kv state + k_sum via f16 MFMA
// Inputs now TRANSPOSED [col=256][M=65536]: per-thread k/v loads are one half8 (16B).
// Output kvout [b][h][d=32][f=128] (K-major B-operand for attn).
__global__ __launch_bounds__(256) void kv_mfma_kernel(const _Float16* __restrict__ kin,
                                                      const _Float16* __restrict__ vin,
                                                      float* __restrict__ kvout,
                                                      float* __restrict__ ksum) {
    __shared__ __align__(16) unsigned short Ah[128 * 64];
    __shared__ __align__(16) unsigned short Bh[48 * 64];

    const int t = threadIdx.x;
    const int c8 = blockIdx.x;           // 512-token slab
    const int h = blockIdx.y, b = blockIdx.z;
    const int dp = t & 31;               // channel within head
    const int octet = t >> 5;            // token octet

    if (t < 128) {
        int r = 32 + (t & 15);
        int oc = t >> 4;
        int off = r * 64 + (((oc ^ ((r >> 3) & 7)) & 7) * 8);
        unsigned short fill = (r == 32) ? (unsigned short)0x3C00 : (unsigned short)0;
        u16x8 z = {fill, fill, fill, fill, fill, fill, fill, fill};
        *(u16x8*)&Bh[off] = z;
    }

    float cbv[8], sbv[8];
#pragma unroll
    for (int i = 0; i < 8; i++) {
        float ang = (PI2F / 64.f) * (float)(octet * 8 + i);
        cbv[i] = cosf(ang);
        sbv[i] = sinf(ang);
    }

    const int lane = t & 63;
    const int wv = t >> 6;
    const int mrow = lane & 15;
    const int kq = lane >> 4;

    f32x4 acc[2][3];
#pragma unroll
    for (int mi = 0; mi < 2; mi++)
#pragma unroll
        for (int ni = 0; ni < 3; ni++) acc[mi][ni] = (f32x4){0.f, 0.f, 0.f, 0.f};

    int offA[4];
#pragma unroll
    for (int tvar = 0; tvar < 4; tvar++) {
        int f = tvar * 32 + dp;
        offA[tvar] = f * 64 + (((octet ^ ((f >> 3) & 7)) & 7) * 8);
    }
    const int offB = dp * 64 + (((octet ^ ((dp >> 3) & 7)) & 7) * 8);

    const size_t colbase = (size_t)(h * HD_ + dp) * BN_ + (size_t)b * N_;

#pragma unroll 1
    for (int ch = 0; ch < 8; ch++) {
        const int n0 = c8 * 512 + ch * 64;
        const int rrow = n0 >> 6;
        float aang = (PI2F / 64.f) * (float)rrow;
        float ca = cosf(aang), sa = sinf(aang);

        half8 k8 = *(const half8*)(kin + colbase + n0 + octet * 8);
        half8 v8 = *(const half8*)(vin + colbase + n0 + octet * 8);
        float kvl[8];
#pragma unroll
        for (int i = 0; i < 8; i++) kvl[i] = (float)k8[i];

        __syncthreads();

#pragma unroll
        for (int tvar = 0; tvar < 4; tvar++) {
            half8 hv;
#pragma unroll
            for (int i = 0; i < 8; i++) {
                float val = kvl[i] * (tvar == 0 ? ca : tvar == 1 ? sa : tvar == 2 ? cbv[i] : sbv[i]);
                hv[i] = (_Float16)val;
            }
            *(half8*)&Ah[offA[tvar]] = hv;
        }
        *(half8*)&Bh[offB] = v8;
        __syncthreads();

#pragma unroll
        for (int s = 0; s < 2; s++) {
            half8 ah[2], bh[3];
            int koct = s * 4 + kq;
#pragma unroll
            for (int mi = 0; mi < 2; mi++) {
                int f = (wv * 2 + mi) * 16 + mrow;
                ah[mi] = *(const half8*)&Ah[f * 64 + (((koct ^ ((f >> 3) & 7)) & 7) * 8)];
            }
#pragma unroll
            for (int ni = 0; ni < 3; ni++) {
                int nr = ni * 16 + mrow;
                bh[ni] = *(const half8*)&Bh[nr * 64 + (((koct ^ ((nr >> 3) & 7)) & 7) * 8)];
            }
#pragma unroll
            for (int mi = 0; mi < 2; mi++)
#pragma unroll
                for (int ni = 0; ni < 3; ni++)
                    acc[mi][ni] = __builtin_amdgcn_mfma_f32_16x16x32_f16(ah[mi], bh[ni], acc[mi][ni], 0, 0, 0);
        }
    }

    // transposed store: kvout[b][h][d][f]
    float* kvp = kvout + (size_t)(b * NH_ + h) * FHD_ * HD_;
    float* ksp = ksum + (size_t)(b * NH_ + h) * FHD_;
#pragma unroll
    for (int mi = 0; mi < 2; mi++) {
        int mt = wv * 2 + mi;
#pragma unroll
        for (int r = 0; r < 4; r++) {
            int f = mt * 16 + kq * 4 + r;
            atomicAdd(&kvp[(size_t)mrow * FHD_ + f], acc[mi][0][r]);
            atomicAdd(&kvp[(size_t)(16 + mrow) * FHD_ + f], acc[mi][1][r]);
            if (mrow == 0) atomicAdd(&ksp[f], acc[mi][2][r]);
        }
    }
}

// ---------------------------------------------------------------- attention lookup via MFMA -> f16
__global__ __launch_bounds__(256) void attn_kernel(const _Float16* __restrict__ qbuf,
                                                   const float* __restrict__ kvin,
                                                   const float* __restrict__ ksum,
                                                   _Float16* __restrict__ ob) {
    __shared__ __align__(16) unsigned short Aq[128 * 128];   // 32 KB
    __shared__ __align__(16) unsigned short Bk[48 * 128];    // 12 KB
    __shared__ float zS[128];

    const int chunk = blockIdx.x;
    const int h = blockIdx.y, b = blockIdx.z;
    const int t = threadIdx.x;
    const int n0 = chunk * 128;

    // ---- stage B
    {
        const float* kvp = kvin + ((size_t)(b * NH_ + h)) * (HD_ * FHD_);
        int d = t >> 3;            // 0..31
        int c0 = (t & 7) * 2;
#pragma unroll
        for (int cc = 0; cc < 2; cc++) {
            int c = c0 + cc;
            const float* src = kvp + (size_t)d * FHD_ + c * 8;
            half8 hv;
#pragma unroll
            for (int i = 0; i < 8; i++) hv[i] = (_Float16)abs_clamp(src[i]);
            *(half8*)&Bk[d * 128 + ((c ^ (d & 7)) * 8)] = hv;
        }
        if (t < 16) {
            const float* ks = ksum + ((size_t)(b * NH_ + h)) * FHD_ + t * 8;
            half8 hv;
#pragma unroll
            for (int i = 0; i < 8; i++) hv[i] = (_Float16)ks[i];
            *(half8*)&Bk[32 * 128 + (t * 8)] = hv;
        } else {
            int idx = t - 16;
            int r = 33 + (idx >> 4), c = idx & 15;
            half8 z = {};
            *(half8*)&Bk[r * 128 + ((c ^ (r & 7)) * 8)] = z;
        }
    }
    // ---- stage A: q_ expanded [tok][f], f16, swizzled
    {
        int tok = t >> 1, hf = t & 1;
        int n = n0 + tok;
        const _Float16* qp = qbuf + ((size_t)b * N_ + n) * CF_ + h * HD_;
        half8 q0 = *(const half8*)(qp + 0);
        half8 q1 = *(const half8*)(qp + 8);
        half8 q2 = *(const half8*)(qp + 16);
        half8 q3 = *(const half8*)(qp + 24);
        float f0, f1;
        if (hf == 0) {
            float aa = (PI2F / 64.f) * (float)(n >> 6);
            f0 = cosf(aa); f1 = sinf(aa);
        } else {
            float ab = (PI2F / 64.f) * (float)(n & 63);
            f0 = cosf(ab); f1 = sinf(ab);
        }
#pragma unroll
        for (int ti = 0; ti < 2; ti++) {
            float fac = ti ? f1 : f0;
#pragma unroll
            for (int dc = 0; dc < 4; dc++) {
                half8 qv = (dc == 0) ? q0 : (dc == 1) ? q1 : (dc == 2) ? q2 : q3;
                half8 hv;
#pragma unroll
                for (int i = 0; i < 8; i++) hv[i] = (_Float16)((float)qv[i] * fac);
                int c = hf * 8 + ti * 4 + dc;
                *(half8*)&Aq[tok * 128 + ((c ^ (tok & 7)) * 8)] = hv;
            }
        }
    }
    __syncthreads();

    const int lane = t & 63;
    const int wv = t >> 6;
    const int mrow = lane & 15;
    const int kq = lane >> 4;

    f32x4 acc[2][3];
#pragma unroll
    for (int mi = 0; mi < 2; mi++)
#pragma unroll
        for (int ni = 0; ni < 3; ni++) acc[mi][ni] = (f32x4){0.f, 0.f, 0.f, 0.f};

#pragma unroll
    for (int ks = 0; ks < 4; ks++) {
        half8 ah[2], bh[3];
        int cpos = ks * 4 + kq;
#pragma unroll
        for (int mi = 0; mi < 2; mi++) {
            int row = wv * 32 + mi * 16 + mrow;
            ah[mi] = *(const half8*)&Aq[row * 128 + ((cpos ^ (row & 7)) * 8)];
        }
#pragma unroll
        for (int ni = 0; ni < 3; ni++) {
            int row = ni * 16 + mrow;
            bh[ni] = *(const half8*)&Bk[row * 128 + ((cpos ^ (row & 7)) * 8)];
        }
#pragma unroll
        for (int mi = 0; mi < 2; mi++)
#pragma unroll
            for (int ni = 0; ni < 3; ni++)
                acc[mi][ni] = __builtin_amdgcn_mfma_f32_16x16x32_f16(ah[mi], bh[ni], acc[mi][ni], 0, 0, 0);
    }

    if (mrow == 0) {
#pragma unroll
        for (int mi = 0; mi < 2; mi++)
#pragma unroll
            for (int r = 0; r < 4; r++)
                zS[wv * 32 + mi * 16 + kq * 4 + r] = acc[mi][2][r];
    }
    __syncthreads();

#pragma unroll
    for (int mi = 0; mi < 2; mi++) {
#pragma unroll
        for (int r = 0; r < 4; r++) {
            int tok = wv * 32 + mi * 16 + kq * 4 + r;
            float z = abs_clamp(1.f / (zS[tok] + EPS_));
            float v0 = abs_clamp(abs_clamp(acc[mi][0][r]) * z);
            float v1 = abs_clamp(abs_clamp(acc[mi][1][r]) * z);
            size_t base = ((size_t)b * N_ + n0 + tok) * CF_ + h * HD_;
            ob[base + mrow] = (_Float16)v0;
            ob[base + 16 + mrow] = (_Float16)v1;
        }
    }
}

// ----------------------------------------------------------------
extern "C" void kernel_launch(void* const* d_in, const int* in_sizes, int n_in,
                              void* d_out, int out_size, void* d_ws, size_t ws_size,
                              hipStream_t stream) {
    (void)in_sizes; (void)n_in; (void)out_size; (void)ws_size;
    const float* query = (const float*)d_in[0];
    const float* Wq = (const float*)d_in[1];
    const float* bq = (const float*)d_in[2];
    const float* Wk = (const float*)d_in[3];
    const float* bk = (const float*)d_in[4];
    const float* Wv = (const float*)d_in[5];
    const float* bv = (const float*)d_in[6];
    const float* Wo = (const float*)d_in[7];
    const float* bo = (const float*)d_in[8];
    const float* Wse1 = (const float*)d_in[9];
    const float* Wse2 = (const float*)d_in[10];
    float* out = (float*)d_out;

    unsigned char* ws = (unsigned char*)d_ws;
    const size_t MB = 1024ull * 1024ull;
    // q16 [65536,512] f16 @0 (64 MiB). Dead after gemm_qkv; ob [65536,256] f16
    // aliased onto it (attn runs strictly after gemm_qkv; single stream).
    _Float16* q16 = (_Float16*)(ws + 0);
    _Float16* ob  = (_Float16*)(ws + 0);
    _Float16* qb  = (_Float16*)(ws + 64 * MB);   // [65536,256] f16
    _Float16* kbT = (_Float16*)(ws + 96 * MB);   // [256,65536] f16 (transposed)
    _Float16* vbT = (_Float16*)(ws + 128 * MB);  // [256,65536] f16 (transposed)
    _Float16* wcat = (_Float16*)(ws + 160 * MB);            // [768,512] f16
    _Float16* wo16 = (_Float16*)(ws + 160 * MB + 786432);   // [512,256] f16
    float* kvb = (float*)(ws + 161 * MB);                   // [16,8,32,128] f32
    float* ksb = (float*)(ws + 163 * MB);                   // [16,8,128]
    float* ssb = (float*)(ws + 163 * MB + 65536);           // [16,512]
    float* sgb = (float*)(ws + 163 * MB + 98304);           // [16,512]

    hipMemsetAsync(kvb, 0, 2097152 + 65536 + 32768, stream);

    convert_w<<<2048, 256, 0, stream>>>(Wq, Wk, Wv, Wo, wcat, wo16);
    se_sum_kernel<<<dim3(B_, 16), 256, 0, stream>>>(query, ssb, q16);
    se_gate_kernel<<<B_, 256, 0, stream>>>(ssb, Wse1, Wse2, sgb);
    gemm_qkv<<<dim3(6, 512), 256, 0, stream>>>(q16, wcat, bq, bk, bv, qb, kbT, vbT);
    kv_mfma_kernel<<<dim3(8, NH_, B_), 256, 0, stream>>>(kbT, vbT, kvb, ksb);
    attn_kernel<<<dim3(32, NH_, B_), 256, 0, stream>>>(qb, kvb, ksb, ob);
    gemm_out<<<dim3(4, 512), 256, 0, stream>>>(ob, wo16, bo, sgb, out);
}